// Round 1
// baseline (1805.987 us; speedup 1.0000x reference)
//
#include <hip/hip_runtime.h>
#include <math.h>

#define BN   1024
#define NB   32
#define KNN  20
#define NROWS (NB*BN)

__device__ __forceinline__ float finf() { return __builtin_huge_valf(); }

// Select the 20 smallest of 1024 distances held wave-wide as dist[t] = d(row, j=t*64+lane).
// Tie-break: smaller j wins (matches jax.lax.top_k stability). All lanes agree after butterfly.
__device__ __forceinline__ void select20(float (&dist)[16], int lane, int* __restrict__ idx_out) {
  for (int e = 0; e < KNN; ++e) {
    float bd = dist[0]; int bt = 0;
#pragma unroll
    for (int t = 1; t < 16; ++t) { if (dist[t] < bd) { bd = dist[t]; bt = t; } }
    int bj = (bt << 6) | lane;
#pragma unroll
    for (int off = 32; off >= 1; off >>= 1) {
      float od = __shfl_xor(bd, off, 64);
      int   oj = __shfl_xor(bj, off, 64);
      if (od < bd || (od == bd && oj < bj)) { bd = od; bj = oj; }
    }
    if (lane == 0) idx_out[e] = bj;
    if ((bj & 63) == lane) {                 // owning lane invalidates (constant-indexed: rule #20)
      int tt = bj >> 6;
#pragma unroll
      for (int t = 0; t < 16; ++t) { if (t == tt) dist[t] = finf(); }
    }
  }
}

// ---------------- kNN on 3-D coords: one wave per row ----------------
__global__ __launch_bounds__(256) void knn3_kernel(const float* __restrict__ x, int* __restrict__ idxo) {
  const int wave = blockIdx.x * 4 + (threadIdx.x >> 6);
  const int lane = threadIdx.x & 63;
  const int b = wave >> 10, i = wave & (BN - 1);
  const float* xb = x + (size_t)b * BN * 3;
  const float xi0 = xb[i*3+0], xi1 = xb[i*3+1], xi2 = xb[i*3+2];
  const float sqi = xi0*xi0 + xi1*xi1 + xi2*xi2;
  float dist[16];
#pragma unroll
  for (int t = 0; t < 16; ++t) {
    const int j = (t << 6) | lane;
    const float a0 = xb[j*3+0], a1 = xb[j*3+1], a2 = xb[j*3+2];
    const float sqj = a0*a0 + a1*a1 + a2*a2;
    const float dt  = xi0*a0 + xi1*a1 + xi2*a2;
    const float d   = sqi + sqj - 2.0f*dt;        // reference formula
    dist[t] = (j == i) ? finf() : d;
  }
  select20(dist, lane, idxo + (size_t)wave * KNN);
}

// ---------------- EdgeConv1: lane = channel, W2/W3 columns in VGPRs ----------------
__global__ __launch_bounds__(256) void edge1_kernel(const float* __restrict__ x, const int* __restrict__ idx,
    const float* __restrict__ W1, const float* __restrict__ B1,
    const float* __restrict__ W2, const float* __restrict__ B2,
    const float* __restrict__ W3, const float* __restrict__ B3,
    float* __restrict__ out1) {
  __shared__ float sh1[4][64];
  __shared__ float sh2[4][64];
  const int lane = threadIdx.x & 63, w = threadIdx.x >> 6;
  float w1c[6], w2c[64], w3c[64];
#pragma unroll
  for (int c = 0; c < 6;  ++c) w1c[c] = W1[c*64 + lane];
#pragma unroll
  for (int c = 0; c < 64; ++c) w2c[c] = W2[c*64 + lane];
#pragma unroll
  for (int c = 0; c < 64; ++c) w3c[c] = W3[c*64 + lane];
  const float b1o = B1[lane], b2o = B2[lane], b3o = B3[lane];
  const int wave = blockIdx.x * 4 + w;
  for (int s = 0; s < 8; ++s) {
    const int row = wave * 8 + s;
    const int b = row >> 10, i = row & (BN - 1);
    const float* xb = x + (size_t)b * BN * 3;
    const float xi0 = xb[i*3+0], xi1 = xb[i*3+1], xi2 = xb[i*3+2];
    float m = 0.0f;                                   // relu outputs are >= 0
    for (int e = 0; e < KNN; ++e) {
      const int j = idx[(size_t)row * KNN + e];
      const float h3 = xb[j*3+0] - xi0, h4 = xb[j*3+1] - xi1, h5 = xb[j*3+2] - xi2;
      float z = b1o + xi0*w1c[0] + xi1*w1c[1] + xi2*w1c[2]
                    + h3*w1c[3] + h4*w1c[4] + h5*w1c[5];
      z = fmaxf(z, 0.0f);
      sh1[w][lane] = z;
      __syncthreads();
      float z2 = b2o;
      const float4* p = (const float4*)sh1[w];
#pragma unroll
      for (int c = 0; c < 16; ++c) {
        const float4 v = p[c];
        z2 += v.x*w2c[4*c+0] + v.y*w2c[4*c+1] + v.z*w2c[4*c+2] + v.w*w2c[4*c+3];
      }
      z2 = fmaxf(z2, 0.0f);
      sh2[w][lane] = z2;
      __syncthreads();
      float z3 = b3o;
      const float4* q = (const float4*)sh2[w];
#pragma unroll
      for (int c = 0; c < 16; ++c) {
        const float4 v = q[c];
        z3 += v.x*w3c[4*c+0] + v.y*w3c[4*c+1] + v.z*w3c[4*c+2] + v.w*w3c[4*c+3];
      }
      z3 = fmaxf(z3, 0.0f);
      m = fmaxf(m, z3);
    }
    out1[(size_t)row * 64 + lane] = m;
  }
}

// ---------------- squared norms of the 64-d features ----------------
__global__ __launch_bounds__(256) void sqnorm_kernel(const float* __restrict__ f, float* __restrict__ sq) {
  const int r = blockIdx.x * blockDim.x + threadIdx.x;   // one row per thread
  const float4* p = (const float4*)(f + (size_t)r * 64);
  float s = 0.0f;
#pragma unroll
  for (int c = 0; c < 16; ++c) { const float4 v = p[c]; s += v.x*v.x + v.y*v.y + v.z*v.z + v.w*v.w; }
  sq[r] = s;
}

// ---------------- kNN on 64-d features: 8 waves = 8 rows per block, LDS j-tiles ----------------
__global__ __launch_bounds__(512) void knn64_kernel(const float* __restrict__ f, const float* __restrict__ sq,
    int* __restrict__ idxo) {
  __shared__ float4 tile[64][16];                    // 16 KiB, XOR-swizzled 16B chunks (T2)
  const int tid  = threadIdx.x;
  const int lane = tid & 63, w = tid >> 6;
  const int row  = blockIdx.x * 8 + w;
  const int b = row >> 10, i = row & (BN - 1);
  const float* fb = f + (size_t)b * BN * 64;
  float4 xi[16];
  const float4* xip = (const float4*)(fb + (size_t)i * 64);
#pragma unroll
  for (int c = 0; c < 16; ++c) xi[c] = xip[c];
  const float sqi = sq[row];
  float dist[16];
#pragma unroll
  for (int t = 0; t < 16; ++t) {
    __syncthreads();                                 // protect previous tile's readers
    const float4* src = (const float4*)(fb + (size_t)(t * 64) * 64);
    for (int q = tid; q < 1024; q += 512) {
      const int jl = q >> 4, c4 = q & 15;
      tile[jl][c4 ^ (jl & 7)] = src[q];
    }
    __syncthreads();
    const int j = (t << 6) | lane;
    float dot = 0.0f;
#pragma unroll
    for (int c = 0; c < 16; ++c) {
      const float4 v = tile[lane][c ^ (lane & 7)];
      dot += xi[c].x*v.x + xi[c].y*v.y + xi[c].z*v.z + xi[c].w*v.w;
    }
    const float d = sqi + sq[b*BN + j] - 2.0f*dot;
    dist[t] = (j == i) ? finf() : d;
  }
  select20(dist, lane, idxo + (size_t)row * KNN);
}

// ---------------- EdgeConv2: thread = channel (128), W4 column in VGPRs ----------------
__global__ __launch_bounds__(128) void edge2_kernel(const float* __restrict__ f, const int* __restrict__ idx,
    const float* __restrict__ W4, const float* __restrict__ B4, float* __restrict__ out2) {
  __shared__ float xish[64];
  __shared__ float hsh[128];
  const int o = threadIdx.x;
  float wc[128];
#pragma unroll
  for (int c = 0; c < 128; ++c) wc[c] = W4[(size_t)c*128 + o];
  const float bo = B4[o];
  for (int s = 0; s < 16; ++s) {
    const int row = blockIdx.x * 16 + s;
    const int b = row >> 10, i = row & (BN - 1);
    const float* fb = f + (size_t)b * BN * 64;
    if (o < 64) { const float v = fb[(size_t)i*64 + o]; xish[o] = v; hsh[o] = v; }
    __syncthreads();
    float m = 0.0f;
    for (int e = 0; e < KNN; ++e) {
      const int j = idx[(size_t)row * KNN + e];
      if (o >= 64) hsh[o] = fb[(size_t)j*64 + (o - 64)] - xish[o - 64];
      __syncthreads();
      float z = bo;
      const float4* p = (const float4*)hsh;
#pragma unroll
      for (int c = 0; c < 32; ++c) {
        const float4 v = p[c];
        z += v.x*wc[4*c+0] + v.y*wc[4*c+1] + v.z*wc[4*c+2] + v.w*wc[4*c+3];
      }
      m = fmaxf(m, fmaxf(z, 0.0f));
      __syncthreads();
    }
    out2[(size_t)row * 128 + o] = m;
  }
}

// ---------------- 128->512 pointwise + global max pool (fused, atomicMax on relu'd values) ---------
__global__ __launch_bounds__(512) void pool_kernel(const float* __restrict__ f, const float* __restrict__ Wp,
    const float* __restrict__ bp, float* __restrict__ pooled) {
  __shared__ float xsh[128];
  const int o = threadIdx.x;
  const int b = blockIdx.x >> 3, chunk = blockIdx.x & 7;
  float wc[128];
#pragma unroll
  for (int c = 0; c < 128; ++c) wc[c] = Wp[(size_t)c*512 + o];
  const float bo = bp[o];
  float m = -finf();
  for (int n = chunk * 128; n < chunk * 128 + 128; ++n) {
    if (o < 128) xsh[o] = f[((size_t)b*BN + n)*128 + o];
    __syncthreads();
    float z = bo;
    const float4* p = (const float4*)xsh;
#pragma unroll
    for (int c = 0; c < 32; ++c) {
      const float4 v = p[c];
      z += v.x*wc[4*c+0] + v.y*wc[4*c+1] + v.z*wc[4*c+2] + v.w*wc[4*c+3];
    }
    m = fmaxf(m, z);
    __syncthreads();
  }
  m = fmaxf(m, 0.0f);   // relu(max z) == max relu(z); non-negative -> int-bit atomicMax is order-correct
  atomicMax((int*)(pooled + (size_t)b*512 + o), __float_as_int(m));
}

// ---------------- classifier head 512->256(relu)->40 ----------------
__global__ __launch_bounds__(256) void head_kernel(const float* __restrict__ pooled,
    const float* __restrict__ Wt1, const float* __restrict__ bt1,
    const float* __restrict__ Wt2, const float* __restrict__ bt2,
    float* __restrict__ out) {
  __shared__ float psh[512];
  __shared__ float h1sh[256];
  const int t = threadIdx.x, b = blockIdx.x;
  psh[t]       = pooled[(size_t)b*512 + t];
  psh[t + 256] = pooled[(size_t)b*512 + t + 256];
  __syncthreads();
  float z = bt1[t];
  for (int j = 0; j < 512; ++j) z += psh[j] * Wt1[(size_t)j*256 + t];
  h1sh[t] = fmaxf(z, 0.0f);
  __syncthreads();
  if (t < 40) {
    float z2 = bt2[t];
    for (int j = 0; j < 256; ++j) z2 += h1sh[j] * Wt2[(size_t)j*40 + t];
    out[(size_t)b*40 + t] = z2;
  }
}

extern "C" void kernel_launch(void* const* d_in, const int* in_sizes, int n_in,
                              void* d_out, int out_size, void* d_ws, size_t ws_size,
                              hipStream_t stream) {
  const float* x   = (const float*)d_in[0];
  // d_in[1] = batch indices (unused: equal-sized clouds)
  const float* W1  = (const float*)d_in[2];
  const float* B1  = (const float*)d_in[3];
  const float* W2  = (const float*)d_in[4];
  const float* B2  = (const float*)d_in[5];
  const float* W3  = (const float*)d_in[6];
  const float* B3  = (const float*)d_in[7];
  const float* W4  = (const float*)d_in[8];
  const float* B4  = (const float*)d_in[9];
  const float* Wp  = (const float*)d_in[10];
  const float* bp  = (const float*)d_in[11];
  const float* Wt1 = (const float*)d_in[12];
  const float* bt1 = (const float*)d_in[13];
  const float* Wt2 = (const float*)d_in[14];
  const float* bt2 = (const float*)d_in[15];
  float* out = (float*)d_out;

  // workspace layout (bytes, 256-aligned)
  char* ws = (char*)d_ws;
  const size_t OFF_SQ     = 0;           //  32768*4      = 131072
  const size_t OFF_IDX1   = 131072;      //  32768*20*4   = 2621440
  const size_t OFF_OUT1   = 2752512;     //  32768*64*4   = 8388608
  const size_t OFF_IDX2   = 11141120;    //  32768*20*4   = 2621440
  const size_t OFF_OUT2   = 13762560;    //  32768*128*4  = 16777216
  const size_t OFF_POOLED = 30539776;    //  32*512*4     = 65536
  const size_t WS_NEEDED  = 30605312;
  if (ws_size < WS_NEEDED) return;       // fail loudly (validation will catch it)

  float* sqbuf  = (float*)(ws + OFF_SQ);
  int*   idx1   = (int*)  (ws + OFF_IDX1);
  float* out1   = (float*)(ws + OFF_OUT1);
  int*   idx2   = (int*)  (ws + OFF_IDX2);
  float* out2   = (float*)(ws + OFF_OUT2);
  float* pooled = (float*)(ws + OFF_POOLED);

  knn3_kernel  <<<NROWS/4,        256, 0, stream>>>(x, idx1);
  edge1_kernel <<<NROWS/(4*8),    256, 0, stream>>>(x, idx1, W1, B1, W2, B2, W3, B3, out1);
  sqnorm_kernel<<<NROWS/256,      256, 0, stream>>>(out1, sqbuf);
  knn64_kernel <<<NROWS/8,        512, 0, stream>>>(out1, sqbuf, idx2);
  edge2_kernel <<<NROWS/16,       128, 0, stream>>>(out1, idx2, W4, B4, out2);
  hipMemsetAsync(pooled, 0, NB*512*sizeof(float), stream);
  pool_kernel  <<<NB*8,           512, 0, stream>>>(out2, Wp, bp, pooled);
  head_kernel  <<<NB,             256, 0, stream>>>(pooled, Wt1, bt1, Wt2, bt2, out);
}

// Round 2
// 1321.367 us; speedup vs baseline: 1.3668x; 1.3668x over previous
//
#include <hip/hip_runtime.h>
#include <math.h>

#define BN   1024
#define NB   32
#define KNN  20
#define NROWS (NB*BN)

typedef __attribute__((ext_vector_type(8))) short bf16x8_t;   // 8 bf16 (4 VGPRs)
typedef __attribute__((ext_vector_type(4))) float f32x4_t;    // MFMA accumulator

__device__ __forceinline__ float finf() { return __builtin_huge_valf(); }

__device__ __forceinline__ unsigned short f2bf(float f) {     // RTNE f32 -> bf16 bits
  union { float f; unsigned u; } v; v.f = f;
  unsigned r = v.u + 0x7FFFu + ((v.u >> 16) & 1u);
  return (unsigned short)(r >> 16);
}

// Select the 20 smallest of 1024 distances held wave-wide as dist[t] = d(row, j=t*64+lane).
// Tie-break: smaller j wins (matches jax.lax.top_k stability). All lanes agree after butterfly.
__device__ __forceinline__ void select20(float (&dist)[16], int lane, int* __restrict__ idx_out) {
  for (int e = 0; e < KNN; ++e) {
    float bd = dist[0]; int bt = 0;
#pragma unroll
    for (int t = 1; t < 16; ++t) { if (dist[t] < bd) { bd = dist[t]; bt = t; } }
    int bj = (bt << 6) | lane;
#pragma unroll
    for (int off = 32; off >= 1; off >>= 1) {
      float od = __shfl_xor(bd, off, 64);
      int   oj = __shfl_xor(bj, off, 64);
      if (od < bd || (od == bd && oj < bj)) { bd = od; bj = oj; }
    }
    if (lane == 0) idx_out[e] = bj;
    if ((bj & 63) == lane) {                 // owning lane invalidates (constant-indexed: rule #20)
      int tt = bj >> 6;
#pragma unroll
      for (int t = 0; t < 16; ++t) { if (t == tt) dist[t] = finf(); }
    }
  }
}

// ---------------- kNN on 3-D coords: one wave per row ----------------
__global__ __launch_bounds__(256) void knn3_kernel(const float* __restrict__ x, int* __restrict__ idxo) {
  const int wave = blockIdx.x * 4 + (threadIdx.x >> 6);
  const int lane = threadIdx.x & 63;
  const int b = wave >> 10, i = wave & (BN - 1);
  const float* xb = x + (size_t)b * BN * 3;
  const float xi0 = xb[i*3+0], xi1 = xb[i*3+1], xi2 = xb[i*3+2];
  const float sqi = xi0*xi0 + xi1*xi1 + xi2*xi2;
  float dist[16];
#pragma unroll
  for (int t = 0; t < 16; ++t) {
    const int j = (t << 6) | lane;
    const float a0 = xb[j*3+0], a1 = xb[j*3+1], a2 = xb[j*3+2];
    const float sqj = a0*a0 + a1*a1 + a2*a2;
    const float dt  = xi0*a0 + xi1*a1 + xi2*a2;
    const float d   = sqi + sqj - 2.0f*dt;        // reference formula
    dist[t] = (j == i) ? finf() : d;
  }
  select20(dist, lane, idxo + (size_t)wave * KNN);
}

// ---------------- EdgeConv1: lane = channel, W2/W3 columns in VGPRs ----------------
// sh1/sh2 slices are strictly per-wave; CDNA wave64 is lockstep, so no block barrier
// is needed — wave_barrier is a free compile-time fence (no runtime cost).
__global__ __launch_bounds__(256) void edge1_kernel(const float* __restrict__ x, const int* __restrict__ idx,
    const float* __restrict__ W1, const float* __restrict__ B1,
    const float* __restrict__ W2, const float* __restrict__ B2,
    const float* __restrict__ W3, const float* __restrict__ B3,
    float* __restrict__ out1) {
  __shared__ float sh1[4][64];
  __shared__ float sh2[4][64];
  const int lane = threadIdx.x & 63, w = threadIdx.x >> 6;
  float w1c[6], w2c[64], w3c[64];
#pragma unroll
  for (int c = 0; c < 6;  ++c) w1c[c] = W1[c*64 + lane];
#pragma unroll
  for (int c = 0; c < 64; ++c) w2c[c] = W2[c*64 + lane];
#pragma unroll
  for (int c = 0; c < 64; ++c) w3c[c] = W3[c*64 + lane];
  const float b1o = B1[lane], b2o = B2[lane], b3o = B3[lane];
  const int wave = blockIdx.x * 4 + w;
  for (int s = 0; s < 8; ++s) {
    const int row = wave * 8 + s;
    const int b = row >> 10, i = row & (BN - 1);
    const float* xb = x + (size_t)b * BN * 3;
    const float xi0 = xb[i*3+0], xi1 = xb[i*3+1], xi2 = xb[i*3+2];
    float m = 0.0f;                                   // relu outputs are >= 0
    for (int e = 0; e < KNN; ++e) {
      const int j = idx[(size_t)row * KNN + e];
      const float h3 = xb[j*3+0] - xi0, h4 = xb[j*3+1] - xi1, h5 = xb[j*3+2] - xi2;
      float z = b1o + xi0*w1c[0] + xi1*w1c[1] + xi2*w1c[2]
                    + h3*w1c[3] + h4*w1c[4] + h5*w1c[5];
      z = fmaxf(z, 0.0f);
      sh1[w][lane] = z;
      __builtin_amdgcn_wave_barrier();
      float z2 = b2o;
      const float4* p = (const float4*)sh1[w];
#pragma unroll
      for (int c = 0; c < 16; ++c) {
        const float4 v = p[c];
        z2 += v.x*w2c[4*c+0] + v.y*w2c[4*c+1] + v.z*w2c[4*c+2] + v.w*w2c[4*c+3];
      }
      z2 = fmaxf(z2, 0.0f);
      sh2[w][lane] = z2;
      __builtin_amdgcn_wave_barrier();
      float z3 = b3o;
      const float4* q = (const float4*)sh2[w];
#pragma unroll
      for (int c = 0; c < 16; ++c) {
        const float4 v = q[c];
        z3 += v.x*w3c[4*c+0] + v.y*w3c[4*c+1] + v.z*w3c[4*c+2] + v.w*w3c[4*c+3];
      }
      z3 = fmaxf(z3, 0.0f);
      m = fmaxf(m, z3);
    }
    out1[(size_t)row * 64 + lane] = m;
  }
}

// ---------------- squared norms of the 64-d features ----------------
__global__ __launch_bounds__(256) void sqnorm_kernel(const float* __restrict__ f, float* __restrict__ sq) {
  const int r = blockIdx.x * blockDim.x + threadIdx.x;   // one row per thread
  const float4* p = (const float4*)(f + (size_t)r * 64);
  float s = 0.0f;
#pragma unroll
  for (int c = 0; c < 16; ++c) { const float4 v = p[c]; s += v.x*v.x + v.y*v.y + v.z*v.z + v.w*v.w; }
  sq[r] = s;
}

// ---------------- kNN on 64-d features: 8 waves = 8 rows per block, LDS j-tiles ----------------
__global__ __launch_bounds__(512) void knn64_kernel(const float* __restrict__ f, const float* __restrict__ sq,
    int* __restrict__ idxo) {
  __shared__ float4 tile[64][16];                    // 16 KiB, XOR-swizzled 16B chunks (T2)
  const int tid  = threadIdx.x;
  const int lane = tid & 63, w = tid >> 6;
  const int row  = blockIdx.x * 8 + w;
  const int b = row >> 10, i = row & (BN - 1);
  const float* fb = f + (size_t)b * BN * 64;
  float4 xi[16];
  const float4* xip = (const float4*)(fb + (size_t)i * 64);
#pragma unroll
  for (int c = 0; c < 16; ++c) xi[c] = xip[c];
  const float sqi = sq[row];
  float dist[16];
#pragma unroll
  for (int t = 0; t < 16; ++t) {
    __syncthreads();                                 // protect previous tile's readers
    const float4* src = (const float4*)(fb + (size_t)(t * 64) * 64);
    for (int q = tid; q < 1024; q += 512) {
      const int jl = q >> 4, c4 = q & 15;
      tile[jl][c4 ^ (jl & 7)] = src[q];
    }
    __syncthreads();
    const int j = (t << 6) | lane;
    float dot = 0.0f;
#pragma unroll
    for (int c = 0; c < 16; ++c) {
      const float4 v = tile[lane][c ^ (lane & 7)];
      dot += xi[c].x*v.x + xi[c].y*v.y + xi[c].z*v.z + xi[c].w*v.w;
    }
    const float d = sqi + sq[b*BN + j] - 2.0f*dot;
    dist[t] = (j == i) ? finf() : d;
  }
  select20(dist, lane, idxo + (size_t)row * KNN);
}

// ---------------- EdgeConv2 as bf16 MFMA GEMM ----------------
// Block = 4 nodes x 20 edges = 80 rows = 5 M-tiles of 16. K=128 (4 k-steps), N=128 (8 n-tiles).
// 4 waves; wave w owns n-tiles {2w, 2w+1} with W4 B-fragments in VGPRs.
// H staged in LDS bf16 with 16B-chunk XOR swizzle (A-frag ds_read_b128 would be 16-way conflicted).
__global__ __launch_bounds__(256) void edge2_mfma_kernel(const float* __restrict__ f, const int* __restrict__ idx,
    const float* __restrict__ W4, const float* __restrict__ B4, float* __restrict__ out2) {
  __shared__ unsigned short Hs[80*128];   // bf16 bits, swizzled: [r][chunk^(r&7)][0..7]
  __shared__ float Zs[80][132];           // +4 pad -> write/read conflicts 2-way (free)
  const int t = threadIdx.x, lane = t & 63, w = t >> 6;
  const int node0 = blockIdx.x * 4;

  // --- B fragments: B[k][n] = W4[k][n]; lane slot e holds W4[ks*32+(lane>>4)*8+e][nt*16+(lane&15)]
  bf16x8_t Bfrag[2][4];
  const int bcol  = lane & 15;
  const int krow0 = (lane >> 4) * 8;
#pragma unroll
  for (int nti = 0; nti < 2; ++nti) {
    const int nt = 2*w + nti;
#pragma unroll
    for (int ks = 0; ks < 4; ++ks) {
#pragma unroll
      for (int e = 0; e < 8; ++e) {
        const int k = ks*32 + krow0 + e;
        Bfrag[nti][ks][e] = (short)f2bf(W4[(size_t)k*128 + nt*16 + bcol]);
      }
    }
  }

  // --- gather + concat H = [xi | xj - xi] into swizzled LDS
  for (int r = w; r < 80; r += 4) {
    const int g = (r * 205) >> 12;          // r/20 for r<80
    const int e = r - g*20;
    const int node = node0 + g;
    const int b = node >> 10;
    const int j = idx[(size_t)node*KNN + e];
    const float xi = f[(size_t)node*64 + lane];
    const float xj = f[((size_t)(b*BN + j))*64 + lane];
    const int c1 = lane, c2 = 64 + lane;
    Hs[r*128 + (((c1>>3) ^ (r&7))<<3) + (c1&7)] = f2bf(xi);
    Hs[r*128 + (((c2>>3) ^ (r&7))<<3) + (c2&7)] = f2bf(xj - xi);
  }
  __syncthreads();

  // --- MFMA: acc[mt][nti] += A(mt,ks) * B(nti,ks)
  f32x4_t acc[5][2];
#pragma unroll
  for (int mt = 0; mt < 5; ++mt) { acc[mt][0] = (f32x4_t){0,0,0,0}; acc[mt][1] = (f32x4_t){0,0,0,0}; }
#pragma unroll
  for (int ks = 0; ks < 4; ++ks) {
#pragma unroll
    for (int mt = 0; mt < 5; ++mt) {
      const int r = mt*16 + (lane & 15);
      const int chunk = ks*4 + (lane >> 4);            // 8 bf16 = exactly one 16B chunk
      const bf16x8_t a = *(const bf16x8_t*)&Hs[r*128 + ((chunk ^ (r&7))<<3)];
      acc[mt][0] = __builtin_amdgcn_mfma_f32_16x16x32_bf16(a, Bfrag[0][ks], acc[mt][0], 0,0,0);
      acc[mt][1] = __builtin_amdgcn_mfma_f32_16x16x32_bf16(a, Bfrag[1][ks], acc[mt][1], 0,0,0);
    }
  }

  // --- bias + relu, scatter to Zs (C/D layout: col=lane&15, row=(lane>>4)*4+reg — m89)
  const int zrow0 = (lane >> 4) * 4;
#pragma unroll
  for (int nti = 0; nti < 2; ++nti) {
    const int col = (2*w + nti)*16 + (lane & 15);
    const float bb = B4[col];
#pragma unroll
    for (int mt = 0; mt < 5; ++mt) {
#pragma unroll
      for (int reg = 0; reg < 4; ++reg) {
        Zs[mt*16 + zrow0 + reg][col] = fmaxf(acc[mt][nti][reg] + bb, 0.0f);
      }
    }
  }
  __syncthreads();

  // --- max over each node's 20 edges; all values >= 0 after relu
#pragma unroll
  for (int p = 0; p < 2; ++p) {
    const int o = t & 127;
    const int g = (t >> 7) + 2*p;
    float m = 0.0f;
#pragma unroll
    for (int e = 0; e < KNN; ++e) m = fmaxf(m, Zs[g*20 + e][o]);
    out2[(size_t)(node0 + g)*128 + o] = m;
  }
}

// ---------------- 128->512 pointwise + global max pool (fused, atomicMax on relu'd values) ---------
__global__ __launch_bounds__(512) void pool_kernel(const float* __restrict__ f, const float* __restrict__ Wp,
    const float* __restrict__ bp, float* __restrict__ pooled) {
  __shared__ float xsh[128];
  const int o = threadIdx.x;
  const int b = blockIdx.x >> 3, chunk = blockIdx.x & 7;
  float wc[128];
#pragma unroll
  for (int c = 0; c < 128; ++c) wc[c] = Wp[(size_t)c*512 + o];
  const float bo = bp[o];
  float m = -finf();
  for (int n = chunk * 128; n < chunk * 128 + 128; ++n) {
    if (o < 128) xsh[o] = f[((size_t)b*BN + n)*128 + o];
    __syncthreads();
    float z = bo;
    const float4* p = (const float4*)xsh;
#pragma unroll
    for (int c = 0; c < 32; ++c) {
      const float4 v = p[c];
      z += v.x*wc[4*c+0] + v.y*wc[4*c+1] + v.z*wc[4*c+2] + v.w*wc[4*c+3];
    }
    m = fmaxf(m, z);
    __syncthreads();
  }
  m = fmaxf(m, 0.0f);   // relu(max z) == max relu(z); non-negative -> int-bit atomicMax is order-correct
  atomicMax((int*)(pooled + (size_t)b*512 + o), __float_as_int(m));
}

// ---------------- classifier head 512->256(relu)->40 ----------------
__global__ __launch_bounds__(256) void head_kernel(const float* __restrict__ pooled,
    const float* __restrict__ Wt1, const float* __restrict__ bt1,
    const float* __restrict__ Wt2, const float* __restrict__ bt2,
    float* __restrict__ out) {
  __shared__ float psh[512];
  __shared__ float h1sh[256];
  const int t = threadIdx.x, b = blockIdx.x;
  psh[t]       = pooled[(size_t)b*512 + t];
  psh[t + 256] = pooled[(size_t)b*512 + t + 256];
  __syncthreads();
  float z = bt1[t];
  for (int j = 0; j < 512; ++j) z += psh[j] * Wt1[(size_t)j*256 + t];
  h1sh[t] = fmaxf(z, 0.0f);
  __syncthreads();
  if (t < 40) {
    float z2 = bt2[t];
    for (int j = 0; j < 256; ++j) z2 += h1sh[j] * Wt2[(size_t)j*40 + t];
    out[(size_t)b*40 + t] = z2;
  }
}

extern "C" void kernel_launch(void* const* d_in, const int* in_sizes, int n_in,
                              void* d_out, int out_size, void* d_ws, size_t ws_size,
                              hipStream_t stream) {
  const float* x   = (const float*)d_in[0];
  // d_in[1] = batch indices (unused: equal-sized clouds)
  const float* W1  = (const float*)d_in[2];
  const float* B1  = (const float*)d_in[3];
  const float* W2  = (const float*)d_in[4];
  const float* B2  = (const float*)d_in[5];
  const float* W3  = (const float*)d_in[6];
  const float* B3  = (const float*)d_in[7];
  const float* W4  = (const float*)d_in[8];
  const float* B4  = (const float*)d_in[9];
  const float* Wp  = (const float*)d_in[10];
  const float* bp  = (const float*)d_in[11];
  const float* Wt1 = (const float*)d_in[12];
  const float* bt1 = (const float*)d_in[13];
  const float* Wt2 = (const float*)d_in[14];
  const float* bt2 = (const float*)d_in[15];
  float* out = (float*)d_out;

  // workspace layout (bytes, 256-aligned)
  char* ws = (char*)d_ws;
  const size_t OFF_SQ     = 0;           //  32768*4      = 131072
  const size_t OFF_IDX1   = 131072;      //  32768*20*4   = 2621440
  const size_t OFF_OUT1   = 2752512;     //  32768*64*4   = 8388608
  const size_t OFF_IDX2   = 11141120;    //  32768*20*4   = 2621440
  const size_t OFF_OUT2   = 13762560;    //  32768*128*4  = 16777216
  const size_t OFF_POOLED = 30539776;    //  32*512*4     = 65536
  const size_t WS_NEEDED  = 30605312;
  if (ws_size < WS_NEEDED) return;       // fail loudly (validation will catch it)

  float* sqbuf  = (float*)(ws + OFF_SQ);
  int*   idx1   = (int*)  (ws + OFF_IDX1);
  float* out1   = (float*)(ws + OFF_OUT1);
  int*   idx2   = (int*)  (ws + OFF_IDX2);
  float* out2   = (float*)(ws + OFF_OUT2);
  float* pooled = (float*)(ws + OFF_POOLED);

  knn3_kernel     <<<NROWS/4,     256, 0, stream>>>(x, idx1);
  edge1_kernel    <<<NROWS/(4*8), 256, 0, stream>>>(x, idx1, W1, B1, W2, B2, W3, B3, out1);
  sqnorm_kernel   <<<NROWS/256,   256, 0, stream>>>(out1, sqbuf);
  knn64_kernel    <<<NROWS/8,     512, 0, stream>>>(out1, sqbuf, idx2);
  edge2_mfma_kernel<<<NROWS/4,    256, 0, stream>>>(out1, idx2, W4, B4, out2);
  hipMemsetAsync(pooled, 0, NB*512*sizeof(float), stream);
  pool_kernel     <<<NB*8,        512, 0, stream>>>(out2, Wp, bp, pooled);
  head_kernel     <<<NB,          256, 0, stream>>>(pooled, Wt1, bt1, Wt2, bt2, out);
}

// Round 3
// 894.436 us; speedup vs baseline: 2.0191x; 1.4773x over previous
//
#include <hip/hip_runtime.h>
#include <math.h>

#define BN   1024
#define NB   32
#define KNN  20
#define NROWS (NB*BN)

typedef __attribute__((ext_vector_type(8))) short bf16x8_t;   // 8 bf16 (4 VGPRs)
typedef __attribute__((ext_vector_type(4))) float f32x4_t;    // MFMA accumulator

__device__ __forceinline__ float finf() { return __builtin_huge_valf(); }

__device__ __forceinline__ unsigned short f2bf(float f) {     // RTNE f32 -> bf16 bits
  union { float f; unsigned u; } v; v.f = f;
  unsigned r = v.u + 0x7FFFu + ((v.u >> 16) & 1u);
  return (unsigned short)(r >> 16);
}
__device__ __forceinline__ float bf2f(unsigned short h) {
  union { unsigned u; float f; } v; v.u = ((unsigned)h) << 16; return v.f;
}

// Select the 20 smallest of 1024 distances held wave-wide as dist[t] = d(row, j=t*64+lane).
// Tie-break: smaller j wins (matches jax.lax.top_k stability). All lanes agree after butterfly.
__device__ __forceinline__ void select20(float (&dist)[16], int lane, int* __restrict__ idx_out) {
  for (int e = 0; e < KNN; ++e) {
    float bd = dist[0]; int bt = 0;
#pragma unroll
    for (int t = 1; t < 16; ++t) { if (dist[t] < bd) { bd = dist[t]; bt = t; } }
    int bj = (bt << 6) | lane;
#pragma unroll
    for (int off = 32; off >= 1; off >>= 1) {
      float od = __shfl_xor(bd, off, 64);
      int   oj = __shfl_xor(bj, off, 64);
      if (od < bd || (od == bd && oj < bj)) { bd = od; bj = oj; }
    }
    if (lane == 0) idx_out[e] = bj;
    if ((bj & 63) == lane) {                 // owning lane invalidates (constant-indexed: rule #20)
      int tt = bj >> 6;
#pragma unroll
      for (int t = 0; t < 16; ++t) { if (t == tt) dist[t] = finf(); }
    }
  }
}

// ---------------- kNN on 3-D coords: one wave per row ----------------
__global__ __launch_bounds__(256) void knn3_kernel(const float* __restrict__ x, int* __restrict__ idxo) {
  const int wave = blockIdx.x * 4 + (threadIdx.x >> 6);
  const int lane = threadIdx.x & 63;
  const int b = wave >> 10, i = wave & (BN - 1);
  const float* xb = x + (size_t)b * BN * 3;
  const float xi0 = xb[i*3+0], xi1 = xb[i*3+1], xi2 = xb[i*3+2];
  const float sqi = xi0*xi0 + xi1*xi1 + xi2*xi2;
  float dist[16];
#pragma unroll
  for (int t = 0; t < 16; ++t) {
    const int j = (t << 6) | lane;
    const float a0 = xb[j*3+0], a1 = xb[j*3+1], a2 = xb[j*3+2];
    const float sqj = a0*a0 + a1*a1 + a2*a2;
    const float dt  = xi0*a0 + xi1*a1 + xi2*a2;
    const float d   = sqi + sqj - 2.0f*dt;        // reference formula
    dist[t] = (j == i) ? finf() : d;
  }
  select20(dist, lane, idxo + (size_t)wave * KNN);
}

// ---------------- EdgeConv1: lane = channel, W2/W3 columns in VGPRs ----------------
__global__ __launch_bounds__(256) void edge1_kernel(const float* __restrict__ x, const int* __restrict__ idx,
    const float* __restrict__ W1, const float* __restrict__ B1,
    const float* __restrict__ W2, const float* __restrict__ B2,
    const float* __restrict__ W3, const float* __restrict__ B3,
    float* __restrict__ out1) {
  __shared__ float sh1[4][64];
  __shared__ float sh2[4][64];
  const int lane = threadIdx.x & 63, w = threadIdx.x >> 6;
  float w1c[6], w2c[64], w3c[64];
#pragma unroll
  for (int c = 0; c < 6;  ++c) w1c[c] = W1[c*64 + lane];
#pragma unroll
  for (int c = 0; c < 64; ++c) w2c[c] = W2[c*64 + lane];
#pragma unroll
  for (int c = 0; c < 64; ++c) w3c[c] = W3[c*64 + lane];
  const float b1o = B1[lane], b2o = B2[lane], b3o = B3[lane];
  const int wave = blockIdx.x * 4 + w;
  for (int s = 0; s < 8; ++s) {
    const int row = wave * 8 + s;
    const int b = row >> 10, i = row & (BN - 1);
    const float* xb = x + (size_t)b * BN * 3;
    const float xi0 = xb[i*3+0], xi1 = xb[i*3+1], xi2 = xb[i*3+2];
    float m = 0.0f;                                   // relu outputs are >= 0
    for (int e = 0; e < KNN; ++e) {
      const int j = idx[(size_t)row * KNN + e];
      const float h3 = xb[j*3+0] - xi0, h4 = xb[j*3+1] - xi1, h5 = xb[j*3+2] - xi2;
      float z = b1o + xi0*w1c[0] + xi1*w1c[1] + xi2*w1c[2]
                    + h3*w1c[3] + h4*w1c[4] + h5*w1c[5];
      z = fmaxf(z, 0.0f);
      sh1[w][lane] = z;
      __builtin_amdgcn_wave_barrier();
      float z2 = b2o;
      const float4* p = (const float4*)sh1[w];
#pragma unroll
      for (int c = 0; c < 16; ++c) {
        const float4 v = p[c];
        z2 += v.x*w2c[4*c+0] + v.y*w2c[4*c+1] + v.z*w2c[4*c+2] + v.w*w2c[4*c+3];
      }
      z2 = fmaxf(z2, 0.0f);
      sh2[w][lane] = z2;
      __builtin_amdgcn_wave_barrier();
      float z3 = b3o;
      const float4* q = (const float4*)sh2[w];
#pragma unroll
      for (int c = 0; c < 16; ++c) {
        const float4 v = q[c];
        z3 += v.x*w3c[4*c+0] + v.y*w3c[4*c+1] + v.z*w3c[4*c+2] + v.w*w3c[4*c+3];
      }
      z3 = fmaxf(z3, 0.0f);
      m = fmaxf(m, z3);
    }
    out1[(size_t)row * 64 + lane] = m;
  }
}

// ---------------- squared norms of the 64-d features ----------------
__global__ __launch_bounds__(256) void sqnorm_kernel(const float* __restrict__ f, float* __restrict__ sq) {
  const int r = blockIdx.x * blockDim.x + threadIdx.x;   // one row per thread
  const float4* p = (const float4*)(f + (size_t)r * 64);
  float s = 0.0f;
#pragma unroll
  for (int c = 0; c < 16; ++c) { const float4 v = p[c]; s += v.x*v.x + v.y*v.y + v.z*v.z + v.w*v.w; }
  sq[r] = s;
}

// ---------------- bf16 hi/lo split of the 64-d features (for bf16x3 MFMA distances) ----------------
__global__ __launch_bounds__(256) void bfsplit_kernel(const float* __restrict__ f,
    unsigned short* __restrict__ hi, unsigned short* __restrict__ lo) {
  const int t = blockIdx.x * 256 + threadIdx.x;     // one float4 per thread
  const float4 v = ((const float4*)f)[t];
  const unsigned short h0 = f2bf(v.x), h1 = f2bf(v.y), h2 = f2bf(v.z), h3 = f2bf(v.w);
  ushort4 hv; hv.x = h0; hv.y = h1; hv.z = h2; hv.w = h3;
  ushort4 lv;
  lv.x = f2bf(v.x - bf2f(h0));   // v - hi is exact (Sterbenz); lo captures next 8 mantissa bits
  lv.y = f2bf(v.y - bf2f(h1));
  lv.z = f2bf(v.z - bf2f(h2));
  lv.w = f2bf(v.w - bf2f(h3));
  ((ushort4*)hi)[t] = hv;
  ((ushort4*)lo)[t] = lv;
}

// ---------------- kNN on 64-d features via bf16x3 MFMA ----------------
// Block = 1024 threads = 16 waves = 16 rows. Wave w computes D[16 rows][64 cols] for
// N-tiles {4w..4w+3} (dot = Ahi*Bhi + Ahi*Blo + Alo*Bhi, fp32 accum), converts to
// distances, transposes through 64KB LDS; then wave w runs select20 on row w.
__global__ __launch_bounds__(1024) void knn64_mfma_kernel(
    const unsigned short* __restrict__ hi, const unsigned short* __restrict__ lo,
    const float* __restrict__ sq, int* __restrict__ idxo) {
  __shared__ float Dmat[16 * 1024];                 // 64 KiB
  const int t = threadIdx.x, lane = t & 63, w = t >> 6;   // w in [0,16)
  const int i0  = blockIdx.x * 16;                  // global row base (blocks never straddle a batch)
  const int b   = i0 >> 10;
  const int i0l = i0 & (BN - 1);

  // A fragments (rows i0..i0+15): row = lane&15, k = ks*32 + (lane>>4)*8 + e
  const size_t arow = (size_t)(i0 + (lane & 15)) * 64;
  const int    koff = (lane >> 4) * 8;
  bf16x8_t Ahi[2], Alo[2];
#pragma unroll
  for (int ks = 0; ks < 2; ++ks) {
    Ahi[ks] = *(const bf16x8_t*)&hi[arow + ks*32 + koff];
    Alo[ks] = *(const bf16x8_t*)&lo[arow + ks*32 + koff];
  }

  f32x4_t acc[4];
#pragma unroll
  for (int nt = 0; nt < 4; ++nt) {
    const int jl = (4*w + nt)*16 + (lane & 15);     // B col -> local node j
    const size_t jrow = ((size_t)(b << 10) + jl) * 64;
    const bf16x8_t Bhi0 = *(const bf16x8_t*)&hi[jrow + koff];
    const bf16x8_t Bhi1 = *(const bf16x8_t*)&hi[jrow + 32 + koff];
    const bf16x8_t Blo0 = *(const bf16x8_t*)&lo[jrow + koff];
    const bf16x8_t Blo1 = *(const bf16x8_t*)&lo[jrow + 32 + koff];
    f32x4_t a = (f32x4_t){0,0,0,0};
    a = __builtin_amdgcn_mfma_f32_16x16x32_bf16(Ahi[0], Bhi0, a, 0,0,0);
    a = __builtin_amdgcn_mfma_f32_16x16x32_bf16(Ahi[1], Bhi1, a, 0,0,0);
    a = __builtin_amdgcn_mfma_f32_16x16x32_bf16(Ahi[0], Blo0, a, 0,0,0);
    a = __builtin_amdgcn_mfma_f32_16x16x32_bf16(Ahi[1], Blo1, a, 0,0,0);
    a = __builtin_amdgcn_mfma_f32_16x16x32_bf16(Alo[0], Bhi0, a, 0,0,0);
    a = __builtin_amdgcn_mfma_f32_16x16x32_bf16(Alo[1], Bhi1, a, 0,0,0);
    acc[nt] = a;
  }

  // distances + transpose into LDS (C/D layout: col=lane&15, row=(lane>>4)*4+reg — m89)
  const int rbase = (lane >> 4) * 4;
  float sqr[4];
#pragma unroll
  for (int r = 0; r < 4; ++r) sqr[r] = sq[i0 + rbase + r];
#pragma unroll
  for (int nt = 0; nt < 4; ++nt) {
    const int jl = (4*w + nt)*16 + (lane & 15);
    const float sqj = sq[(b << 10) + jl];
#pragma unroll
    for (int r = 0; r < 4; ++r) {
      float d = sqr[r] + sqj - 2.0f * acc[nt][r];
      if (jl == i0l + rbase + r) d = finf();        // exclude self
      Dmat[(rbase + r)*1024 + jl] = d;              // 4-way bank conflict, 16 stores once: negligible
    }
  }
  __syncthreads();

  float dist[16];
#pragma unroll
  for (int tt = 0; tt < 16; ++tt) dist[tt] = Dmat[w*1024 + tt*64 + lane];  // 2-way: free
  select20(dist, lane, idxo + (size_t)(i0 + w) * KNN);
}

// ---------------- EdgeConv2 as bf16 MFMA GEMM ----------------
__global__ __launch_bounds__(256) void edge2_mfma_kernel(const float* __restrict__ f, const int* __restrict__ idx,
    const float* __restrict__ W4, const float* __restrict__ B4, float* __restrict__ out2) {
  __shared__ unsigned short Hs[80*128];   // bf16 bits, swizzled: [r][chunk^(r&7)][0..7]
  __shared__ float Zs[80][132];           // +4 pad -> write/read conflicts 2-way (free)
  const int t = threadIdx.x, lane = t & 63, w = t >> 6;
  const int node0 = blockIdx.x * 4;

  bf16x8_t Bfrag[2][4];
  const int bcol  = lane & 15;
  const int krow0 = (lane >> 4) * 8;
#pragma unroll
  for (int nti = 0; nti < 2; ++nti) {
    const int nt = 2*w + nti;
#pragma unroll
    for (int ks = 0; ks < 4; ++ks) {
#pragma unroll
      for (int e = 0; e < 8; ++e) {
        const int k = ks*32 + krow0 + e;
        Bfrag[nti][ks][e] = (short)f2bf(W4[(size_t)k*128 + nt*16 + bcol]);
      }
    }
  }

  for (int r = w; r < 80; r += 4) {
    const int g = (r * 205) >> 12;          // r/20 for r<80
    const int e = r - g*20;
    const int node = node0 + g;
    const int b = node >> 10;
    const int j = idx[(size_t)node*KNN + e];
    const float xi = f[(size_t)node*64 + lane];
    const float xj = f[((size_t)(b*BN + j))*64 + lane];
    const int c1 = lane, c2 = 64 + lane;
    Hs[r*128 + (((c1>>3) ^ (r&7))<<3) + (c1&7)] = f2bf(xi);
    Hs[r*128 + (((c2>>3) ^ (r&7))<<3) + (c2&7)] = f2bf(xj - xi);
  }
  __syncthreads();

  f32x4_t acc[5][2];
#pragma unroll
  for (int mt = 0; mt < 5; ++mt) { acc[mt][0] = (f32x4_t){0,0,0,0}; acc[mt][1] = (f32x4_t){0,0,0,0}; }
#pragma unroll
  for (int ks = 0; ks < 4; ++ks) {
#pragma unroll
    for (int mt = 0; mt < 5; ++mt) {
      const int r = mt*16 + (lane & 15);
      const int chunk = ks*4 + (lane >> 4);
      const bf16x8_t a = *(const bf16x8_t*)&Hs[r*128 + ((chunk ^ (r&7))<<3)];
      acc[mt][0] = __builtin_amdgcn_mfma_f32_16x16x32_bf16(a, Bfrag[0][ks], acc[mt][0], 0,0,0);
      acc[mt][1] = __builtin_amdgcn_mfma_f32_16x16x32_bf16(a, Bfrag[1][ks], acc[mt][1], 0,0,0);
    }
  }

  const int zrow0 = (lane >> 4) * 4;
#pragma unroll
  for (int nti = 0; nti < 2; ++nti) {
    const int col = (2*w + nti)*16 + (lane & 15);
    const float bb = B4[col];
#pragma unroll
    for (int mt = 0; mt < 5; ++mt) {
#pragma unroll
      for (int reg = 0; reg < 4; ++reg) {
        Zs[mt*16 + zrow0 + reg][col] = fmaxf(acc[mt][nti][reg] + bb, 0.0f);
      }
    }
  }
  __syncthreads();

#pragma unroll
  for (int p = 0; p < 2; ++p) {
    const int o = t & 127;
    const int g = (t >> 7) + 2*p;
    float m = 0.0f;
#pragma unroll
    for (int e = 0; e < KNN; ++e) m = fmaxf(m, Zs[g*20 + e][o]);
    out2[(size_t)(node0 + g)*128 + o] = m;
  }
}

// ---------------- 128->512 pointwise + global max pool (fused, atomicMax on relu'd values) ---------
__global__ __launch_bounds__(512) void pool_kernel(const float* __restrict__ f, const float* __restrict__ Wp,
    const float* __restrict__ bp, float* __restrict__ pooled) {
  __shared__ float xsh[128];
  const int o = threadIdx.x;
  const int b = blockIdx.x >> 3, chunk = blockIdx.x & 7;
  float wc[128];
#pragma unroll
  for (int c = 0; c < 128; ++c) wc[c] = Wp[(size_t)c*512 + o];
  const float bo = bp[o];
  float m = -finf();
  for (int n = chunk * 128; n < chunk * 128 + 128; ++n) {
    if (o < 128) xsh[o] = f[((size_t)b*BN + n)*128 + o];
    __syncthreads();
    float z = bo;
    const float4* p = (const float4*)xsh;
#pragma unroll
    for (int c = 0; c < 32; ++c) {
      const float4 v = p[c];
      z += v.x*wc[4*c+0] + v.y*wc[4*c+1] + v.z*wc[4*c+2] + v.w*wc[4*c+3];
    }
    m = fmaxf(m, z);
    __syncthreads();
  }
  m = fmaxf(m, 0.0f);   // relu(max z) == max relu(z); non-negative -> int-bit atomicMax is order-correct
  atomicMax((int*)(pooled + (size_t)b*512 + o), __float_as_int(m));
}

// ---------------- classifier head 512->256(relu)->40 ----------------
__global__ __launch_bounds__(256) void head_kernel(const float* __restrict__ pooled,
    const float* __restrict__ Wt1, const float* __restrict__ bt1,
    const float* __restrict__ Wt2, const float* __restrict__ bt2,
    float* __restrict__ out) {
  __shared__ float psh[512];
  __shared__ float h1sh[256];
  const int t = threadIdx.x, b = blockIdx.x;
  psh[t]       = pooled[(size_t)b*512 + t];
  psh[t + 256] = pooled[(size_t)b*512 + t + 256];
  __syncthreads();
  float z = bt1[t];
  for (int j = 0; j < 512; ++j) z += psh[j] * Wt1[(size_t)j*256 + t];
  h1sh[t] = fmaxf(z, 0.0f);
  __syncthreads();
  if (t < 40) {
    float z2 = bt2[t];
    for (int j = 0; j < 256; ++j) z2 += h1sh[j] * Wt2[(size_t)j*40 + t];
    out[(size_t)b*40 + t] = z2;
  }
}

extern "C" void kernel_launch(void* const* d_in, const int* in_sizes, int n_in,
                              void* d_out, int out_size, void* d_ws, size_t ws_size,
                              hipStream_t stream) {
  const float* x   = (const float*)d_in[0];
  // d_in[1] = batch indices (unused: equal-sized clouds)
  const float* W1  = (const float*)d_in[2];
  const float* B1  = (const float*)d_in[3];
  const float* W2  = (const float*)d_in[4];
  const float* B2  = (const float*)d_in[5];
  const float* W3  = (const float*)d_in[6];
  const float* B3  = (const float*)d_in[7];
  const float* W4  = (const float*)d_in[8];
  const float* B4  = (const float*)d_in[9];
  const float* Wp  = (const float*)d_in[10];
  const float* bp  = (const float*)d_in[11];
  const float* Wt1 = (const float*)d_in[12];
  const float* bt1 = (const float*)d_in[13];
  const float* Wt2 = (const float*)d_in[14];
  const float* bt2 = (const float*)d_in[15];
  float* out = (float*)d_out;

  // workspace layout (bytes, 256-aligned)
  char* ws = (char*)d_ws;
  const size_t OFF_SQ     = 0;           //  32768*4      = 131072
  const size_t OFF_IDX1   = 131072;      //  32768*20*4   = 2621440
  const size_t OFF_OUT1   = 2752512;     //  32768*64*4   = 8388608
  const size_t OFF_IDX2   = 11141120;    //  32768*20*4   = 2621440
  const size_t OFF_OUT2   = 13762560;    //  32768*128*4  = 16777216
  const size_t OFF_POOLED = 30539776;    //  32*512*4     = 65536
  const size_t WS_NEEDED  = 30605312;
  if (ws_size < WS_NEEDED) return;       // fail loudly (validation will catch it)

  float* sqbuf  = (float*)(ws + OFF_SQ);
  int*   idx1   = (int*)  (ws + OFF_IDX1);
  float* out1   = (float*)(ws + OFF_OUT1);
  int*   idx2   = (int*)  (ws + OFF_IDX2);
  float* out2   = (float*)(ws + OFF_OUT2);
  float* pooled = (float*)(ws + OFF_POOLED);
  // hi/lo bf16 split arrays alias the out2 region (4 MB each; out2 is 16.7 MB and is
  // only written by edge2_mfma AFTER knn64_mfma has consumed hi/lo — same stream).
  unsigned short* hib = (unsigned short*)(ws + OFF_OUT2);
  unsigned short* lob = (unsigned short*)(ws + OFF_OUT2 + 4194304);

  knn3_kernel      <<<NROWS/4,     256, 0, stream>>>(x, idx1);
  edge1_kernel     <<<NROWS/(4*8), 256, 0, stream>>>(x, idx1, W1, B1, W2, B2, W3, B3, out1);
  sqnorm_kernel    <<<NROWS/256,   256, 0, stream>>>(out1, sqbuf);
  bfsplit_kernel   <<<NROWS*64/(4*256), 256, 0, stream>>>(out1, hib, lob);
  knn64_mfma_kernel<<<NROWS/16,    1024, 0, stream>>>(hib, lob, sqbuf, idx2);
  edge2_mfma_kernel<<<NROWS/4,     256, 0, stream>>>(out1, idx2, W4, B4, out2);
  hipMemsetAsync(pooled, 0, NB*512*sizeof(float), stream);
  pool_kernel      <<<NB*8,        512, 0, stream>>>(out2, Wp, bp, pooled);
  head_kernel      <<<NB,          256, 0, stream>>>(pooled, Wt1, bt1, Wt2, bt2, out);
}

// Round 4
// 698.253 us; speedup vs baseline: 2.5864x; 1.2810x over previous
//
#include <hip/hip_runtime.h>
#include <math.h>

#define BN   1024
#define NB   32
#define KNN  20
#define NROWS (NB*BN)

typedef __attribute__((ext_vector_type(8))) short bf16x8_t;   // 8 bf16 (4 VGPRs)
typedef __attribute__((ext_vector_type(4))) float f32x4_t;    // MFMA accumulator

__device__ __forceinline__ float finf() { return __builtin_huge_valf(); }

__device__ __forceinline__ unsigned short f2bf(float f) {     // RTNE f32 -> bf16 bits
  union { float f; unsigned u; } v; v.f = f;
  unsigned r = v.u + 0x7FFFu + ((v.u >> 16) & 1u);
  return (unsigned short)(r >> 16);
}
__device__ __forceinline__ float bf2f(unsigned short h) {
  union { unsigned u; float f; } v; v.u = ((unsigned)h) << 16; return v.f;
}

// Select the 20 smallest of 1024 distances held wave-wide as dist[t] = d(row, j=t*64+lane).
// Tie-break: smaller j wins (matches jax.lax.top_k stability). All lanes agree after butterfly.
__device__ __forceinline__ void select20(float (&dist)[16], int lane, int* __restrict__ idx_out) {
  for (int e = 0; e < KNN; ++e) {
    float bd = dist[0]; int bt = 0;
#pragma unroll
    for (int t = 1; t < 16; ++t) { if (dist[t] < bd) { bd = dist[t]; bt = t; } }
    int bj = (bt << 6) | lane;
#pragma unroll
    for (int off = 32; off >= 1; off >>= 1) {
      float od = __shfl_xor(bd, off, 64);
      int   oj = __shfl_xor(bj, off, 64);
      if (od < bd || (od == bd && oj < bj)) { bd = od; bj = oj; }
    }
    if (lane == 0) idx_out[e] = bj;
    if ((bj & 63) == lane) {                 // owning lane invalidates (constant-indexed: rule #20)
      int tt = bj >> 6;
#pragma unroll
      for (int t = 0; t < 16; ++t) { if (t == tt) dist[t] = finf(); }
    }
  }
}

// ---------------- kNN on 3-D coords: one wave per row ----------------
__global__ __launch_bounds__(256) void knn3_kernel(const float* __restrict__ x, int* __restrict__ idxo) {
  const int wave = blockIdx.x * 4 + (threadIdx.x >> 6);
  const int lane = threadIdx.x & 63;
  const int b = wave >> 10, i = wave & (BN - 1);
  const float* xb = x + (size_t)b * BN * 3;
  const float xi0 = xb[i*3+0], xi1 = xb[i*3+1], xi2 = xb[i*3+2];
  const float sqi = xi0*xi0 + xi1*xi1 + xi2*xi2;
  float dist[16];
#pragma unroll
  for (int t = 0; t < 16; ++t) {
    const int j = (t << 6) | lane;
    const float a0 = xb[j*3+0], a1 = xb[j*3+1], a2 = xb[j*3+2];
    const float sqj = a0*a0 + a1*a1 + a2*a2;
    const float dt  = xi0*a0 + xi1*a1 + xi2*a2;
    const float d   = sqi + sqj - 2.0f*dt;        // reference formula
    dist[t] = (j == i) ? finf() : d;
  }
  select20(dist, lane, idxo + (size_t)wave * KNN);
}

// ---------------- EdgeConv1 via MFMA ----------------
// Block = 4 nodes x 20 edges = 80 rows, 4 waves.
// Layer1 (K=6) on VALU, lane=channel, written bf16 into swizzled LDS.
// Layers 2,3 (64x64) via mfma_16x16x32_bf16: wave w owns n-tile w; W2/W3 B-frags in VGPRs.
// Epilogue fuses: max over 20 edges -> out1, bf16 hi/lo split -> hib/lob, sqnorm -> sqbuf.
__global__ __launch_bounds__(256) void edge1_mfma_kernel(const float* __restrict__ x, const int* __restrict__ idx,
    const float* __restrict__ W1, const float* __restrict__ B1,
    const float* __restrict__ W2, const float* __restrict__ B2,
    const float* __restrict__ W3, const float* __restrict__ B3,
    float* __restrict__ out1, unsigned short* __restrict__ hib,
    unsigned short* __restrict__ lob, float* __restrict__ sqbuf) {
  __shared__ unsigned short Hs1[80*64];   // 10 KB, swizzled: [r][(c>>3)^(r&7)][c&7]
  __shared__ unsigned short Hs2[80*64];   // 10 KB
  __shared__ float Zs[80][68];            // 21.25 KB, +4 pad
  const int t = threadIdx.x, lane = t & 63, w = t >> 6;
  const int node0 = blockIdx.x * 4;

  // --- B fragments for layers 2 and 3: col = w*16+(lane&15), k = ks*32+(lane>>4)*8+e
  const int bcol  = w*16 + (lane & 15);
  const int krow0 = (lane >> 4) * 8;
  bf16x8_t Bf2[2], Bf3[2];
#pragma unroll
  for (int ks = 0; ks < 2; ++ks) {
#pragma unroll
    for (int e = 0; e < 8; ++e) {
      const int k = ks*32 + krow0 + e;
      Bf2[ks][e] = (short)f2bf(W2[(size_t)k*64 + bcol]);
      Bf3[ks][e] = (short)f2bf(W3[(size_t)k*64 + bcol]);
    }
  }

  // --- Layer 1 on VALU: lane = channel, 20 rows per wave
  float w1c[6];
#pragma unroll
  for (int c = 0; c < 6; ++c) w1c[c] = W1[c*64 + lane];
  const float b1o = B1[lane];
  for (int r = w; r < 80; r += 4) {
    const int g = (r * 205) >> 12;          // r/20 for r<80
    const int e = r - g*20;
    const int node = node0 + g;
    const int b = node >> 10;
    const int j = idx[(size_t)node*KNN + e];
    const float xi0 = x[(size_t)node*3+0], xi1 = x[(size_t)node*3+1], xi2 = x[(size_t)node*3+2];
    const size_t jr = ((size_t)(b*BN + j))*3;
    const float h3 = x[jr+0]-xi0, h4 = x[jr+1]-xi1, h5 = x[jr+2]-xi2;
    float z = b1o + xi0*w1c[0] + xi1*w1c[1] + xi2*w1c[2]
                  + h3*w1c[3] + h4*w1c[4] + h5*w1c[5];
    z = fmaxf(z, 0.0f);
    Hs1[r*64 + (((lane>>3) ^ (r&7))<<3) + (lane&7)] = f2bf(z);
  }
  __syncthreads();

  // --- Layer 2 MFMA: acc[mt] over 5 m-tiles, K=64 (2 k-steps)
  f32x4_t acc[5];
#pragma unroll
  for (int mt = 0; mt < 5; ++mt) acc[mt] = (f32x4_t){0,0,0,0};
#pragma unroll
  for (int ks = 0; ks < 2; ++ks) {
#pragma unroll
    for (int mt = 0; mt < 5; ++mt) {
      const int r = mt*16 + (lane & 15);
      const int chunk = ks*4 + (lane >> 4);          // k/8
      const bf16x8_t a = *(const bf16x8_t*)&Hs1[r*64 + ((chunk ^ (r&7))<<3)];
      acc[mt] = __builtin_amdgcn_mfma_f32_16x16x32_bf16(a, Bf2[ks], acc[mt], 0,0,0);
    }
  }
  // bias+relu -> bf16 -> Hs2 (C/D: col=lane&15 within tile, row=(lane>>4)*4+reg — m89)
  {
    const float b2o = B2[bcol];
    const int rbase = (lane >> 4) * 4;
#pragma unroll
    for (int mt = 0; mt < 5; ++mt) {
#pragma unroll
      for (int reg = 0; reg < 4; ++reg) {
        const int row = mt*16 + rbase + reg;
        const float v = fmaxf(acc[mt][reg] + b2o, 0.0f);
        Hs2[row*64 + (((bcol>>3) ^ (row&7))<<3) + (bcol&7)] = f2bf(v);
      }
    }
  }
  __syncthreads();

  // --- Layer 3 MFMA
#pragma unroll
  for (int mt = 0; mt < 5; ++mt) acc[mt] = (f32x4_t){0,0,0,0};
#pragma unroll
  for (int ks = 0; ks < 2; ++ks) {
#pragma unroll
    for (int mt = 0; mt < 5; ++mt) {
      const int r = mt*16 + (lane & 15);
      const int chunk = ks*4 + (lane >> 4);
      const bf16x8_t a = *(const bf16x8_t*)&Hs2[r*64 + ((chunk ^ (r&7))<<3)];
      acc[mt] = __builtin_amdgcn_mfma_f32_16x16x32_bf16(a, Bf3[ks], acc[mt], 0,0,0);
    }
  }
  {
    const float b3o = B3[bcol];
    const int rbase = (lane >> 4) * 4;
#pragma unroll
    for (int mt = 0; mt < 5; ++mt) {
#pragma unroll
      for (int reg = 0; reg < 4; ++reg) {
        Zs[mt*16 + rbase + reg][bcol] = fmaxf(acc[mt][reg] + b3o, 0.0f);
      }
    }
  }
  __syncthreads();

  // --- Epilogue: wave w = node g=w, lane = channel. Max over 20 edges (>=0 after relu),
  //     then fused bf16 hi/lo split and sqnorm (wave butterfly).
  {
    const int g = w, o = lane;
    float m = 0.0f;
#pragma unroll
    for (int e = 0; e < KNN; ++e) m = fmaxf(m, Zs[g*20 + e][o]);
    const int node = node0 + g;
    out1[(size_t)node*64 + o] = m;
    const unsigned short h = f2bf(m);
    hib[(size_t)node*64 + o] = h;
    lob[(size_t)node*64 + o] = f2bf(m - bf2f(h));
    float s = m * m;
#pragma unroll
    for (int off = 32; off >= 1; off >>= 1) s += __shfl_xor(s, off, 64);
    if (o == 0) sqbuf[node] = s;
  }
}

// ---------------- kNN on 64-d features via bf16x3 MFMA ----------------
__global__ __launch_bounds__(1024) void knn64_mfma_kernel(
    const unsigned short* __restrict__ hi, const unsigned short* __restrict__ lo,
    const float* __restrict__ sq, int* __restrict__ idxo) {
  __shared__ float Dmat[16 * 1024];                 // 64 KiB
  const int t = threadIdx.x, lane = t & 63, w = t >> 6;   // w in [0,16)
  const int i0  = blockIdx.x * 16;                  // global row base (blocks never straddle a batch)
  const int b   = i0 >> 10;
  const int i0l = i0 & (BN - 1);

  const size_t arow = (size_t)(i0 + (lane & 15)) * 64;
  const int    koff = (lane >> 4) * 8;
  bf16x8_t Ahi[2], Alo[2];
#pragma unroll
  for (int ks = 0; ks < 2; ++ks) {
    Ahi[ks] = *(const bf16x8_t*)&hi[arow + ks*32 + koff];
    Alo[ks] = *(const bf16x8_t*)&lo[arow + ks*32 + koff];
  }

  f32x4_t acc[4];
#pragma unroll
  for (int nt = 0; nt < 4; ++nt) {
    const int jl = (4*w + nt)*16 + (lane & 15);     // B col -> local node j
    const size_t jrow = ((size_t)(b << 10) + jl) * 64;
    const bf16x8_t Bhi0 = *(const bf16x8_t*)&hi[jrow + koff];
    const bf16x8_t Bhi1 = *(const bf16x8_t*)&hi[jrow + 32 + koff];
    const bf16x8_t Blo0 = *(const bf16x8_t*)&lo[jrow + koff];
    const bf16x8_t Blo1 = *(const bf16x8_t*)&lo[jrow + 32 + koff];
    f32x4_t a = (f32x4_t){0,0,0,0};
    a = __builtin_amdgcn_mfma_f32_16x16x32_bf16(Ahi[0], Bhi0, a, 0,0,0);
    a = __builtin_amdgcn_mfma_f32_16x16x32_bf16(Ahi[1], Bhi1, a, 0,0,0);
    a = __builtin_amdgcn_mfma_f32_16x16x32_bf16(Ahi[0], Blo0, a, 0,0,0);
    a = __builtin_amdgcn_mfma_f32_16x16x32_bf16(Ahi[1], Blo1, a, 0,0,0);
    a = __builtin_amdgcn_mfma_f32_16x16x32_bf16(Alo[0], Bhi0, a, 0,0,0);
    a = __builtin_amdgcn_mfma_f32_16x16x32_bf16(Alo[1], Bhi1, a, 0,0,0);
    acc[nt] = a;
  }

  const int rbase = (lane >> 4) * 4;
  float sqr[4];
#pragma unroll
  for (int r = 0; r < 4; ++r) sqr[r] = sq[i0 + rbase + r];
#pragma unroll
  for (int nt = 0; nt < 4; ++nt) {
    const int jl = (4*w + nt)*16 + (lane & 15);
    const float sqj = sq[(b << 10) + jl];
#pragma unroll
    for (int r = 0; r < 4; ++r) {
      float d = sqr[r] + sqj - 2.0f * acc[nt][r];
      if (jl == i0l + rbase + r) d = finf();        // exclude self
      Dmat[(rbase + r)*1024 + jl] = d;
    }
  }
  __syncthreads();

  float dist[16];
#pragma unroll
  for (int tt = 0; tt < 16; ++tt) dist[tt] = Dmat[w*1024 + tt*64 + lane];  // 2-way: free
  select20(dist, lane, idxo + (size_t)(i0 + w) * KNN);
}

// ---------------- EdgeConv2 as bf16 MFMA GEMM ----------------
__global__ __launch_bounds__(256) void edge2_mfma_kernel(const float* __restrict__ f, const int* __restrict__ idx,
    const float* __restrict__ W4, const float* __restrict__ B4, float* __restrict__ out2) {
  __shared__ unsigned short Hs[80*128];   // bf16 bits, swizzled: [r][chunk^(r&7)][0..7]
  __shared__ float Zs[80][132];           // +4 pad -> write/read conflicts 2-way (free)
  const int t = threadIdx.x, lane = t & 63, w = t >> 6;
  const int node0 = blockIdx.x * 4;

  bf16x8_t Bfrag[2][4];
  const int bcol  = lane & 15;
  const int krow0 = (lane >> 4) * 8;
#pragma unroll
  for (int nti = 0; nti < 2; ++nti) {
    const int nt = 2*w + nti;
#pragma unroll
    for (int ks = 0; ks < 4; ++ks) {
#pragma unroll
      for (int e = 0; e < 8; ++e) {
        const int k = ks*32 + krow0 + e;
        Bfrag[nti][ks][e] = (short)f2bf(W4[(size_t)k*128 + nt*16 + bcol]);
      }
    }
  }

  for (int r = w; r < 80; r += 4) {
    const int g = (r * 205) >> 12;          // r/20 for r<80
    const int e = r - g*20;
    const int node = node0 + g;
    const int b = node >> 10;
    const int j = idx[(size_t)node*KNN + e];
    const float xi = f[(size_t)node*64 + lane];
    const float xj = f[((size_t)(b*BN + j))*64 + lane];
    const int c1 = lane, c2 = 64 + lane;
    Hs[r*128 + (((c1>>3) ^ (r&7))<<3) + (c1&7)] = f2bf(xi);
    Hs[r*128 + (((c2>>3) ^ (r&7))<<3) + (c2&7)] = f2bf(xj - xi);
  }
  __syncthreads();

  f32x4_t acc[5][2];
#pragma unroll
  for (int mt = 0; mt < 5; ++mt) { acc[mt][0] = (f32x4_t){0,0,0,0}; acc[mt][1] = (f32x4_t){0,0,0,0}; }
#pragma unroll
  for (int ks = 0; ks < 4; ++ks) {
#pragma unroll
    for (int mt = 0; mt < 5; ++mt) {
      const int r = mt*16 + (lane & 15);
      const int chunk = ks*4 + (lane >> 4);
      const bf16x8_t a = *(const bf16x8_t*)&Hs[r*128 + ((chunk ^ (r&7))<<3)];
      acc[mt][0] = __builtin_amdgcn_mfma_f32_16x16x32_bf16(a, Bfrag[0][ks], acc[mt][0], 0,0,0);
      acc[mt][1] = __builtin_amdgcn_mfma_f32_16x16x32_bf16(a, Bfrag[1][ks], acc[mt][1], 0,0,0);
    }
  }

  const int zrow0 = (lane >> 4) * 4;
#pragma unroll
  for (int nti = 0; nti < 2; ++nti) {
    const int col = (2*w + nti)*16 + (lane & 15);
    const float bb = B4[col];
#pragma unroll
    for (int mt = 0; mt < 5; ++mt) {
#pragma unroll
      for (int reg = 0; reg < 4; ++reg) {
        Zs[mt*16 + zrow0 + reg][col] = fmaxf(acc[mt][nti][reg] + bb, 0.0f);
      }
    }
  }
  __syncthreads();

#pragma unroll
  for (int p = 0; p < 2; ++p) {
    const int o = t & 127;
    const int g = (t >> 7) + 2*p;
    float m = 0.0f;
#pragma unroll
    for (int e = 0; e < KNN; ++e) m = fmaxf(m, Zs[g*20 + e][o]);
    out2[(size_t)(node0 + g)*128 + o] = m;
  }
}

// ---------------- 128->512 pointwise + global max pool (fused, atomicMax on relu'd values) ---------
__global__ __launch_bounds__(512) void pool_kernel(const float* __restrict__ f, const float* __restrict__ Wp,
    const float* __restrict__ bp, float* __restrict__ pooled) {
  __shared__ float xsh[128];
  const int o = threadIdx.x;
  const int b = blockIdx.x >> 3, chunk = blockIdx.x & 7;
  float wc[128];
#pragma unroll
  for (int c = 0; c < 128; ++c) wc[c] = Wp[(size_t)c*512 + o];
  const float bo = bp[o];
  float m = -finf();
  for (int n = chunk * 128; n < chunk * 128 + 128; ++n) {
    if (o < 128) xsh[o] = f[((size_t)b*BN + n)*128 + o];
    __syncthreads();
    float z = bo;
    const float4* p = (const float4*)xsh;
#pragma unroll
    for (int c = 0; c < 32; ++c) {
      const float4 v = p[c];
      z += v.x*wc[4*c+0] + v.y*wc[4*c+1] + v.z*wc[4*c+2] + v.w*wc[4*c+3];
    }
    m = fmaxf(m, z);
    __syncthreads();
  }
  m = fmaxf(m, 0.0f);   // relu(max z) == max relu(z); non-negative -> int-bit atomicMax is order-correct
  atomicMax((int*)(pooled + (size_t)b*512 + o), __float_as_int(m));
}

// ---------------- classifier head 512->256(relu)->40 ----------------
__global__ __launch_bounds__(256) void head_kernel(const float* __restrict__ pooled,
    const float* __restrict__ Wt1, const float* __restrict__ bt1,
    const float* __restrict__ Wt2, const float* __restrict__ bt2,
    float* __restrict__ out) {
  __shared__ float psh[512];
  __shared__ float h1sh[256];
  const int t = threadIdx.x, b = blockIdx.x;
  psh[t]       = pooled[(size_t)b*512 + t];
  psh[t + 256] = pooled[(size_t)b*512 + t + 256];
  __syncthreads();
  float z = bt1[t];
  for (int j = 0; j < 512; ++j) z += psh[j] * Wt1[(size_t)j*256 + t];
  h1sh[t] = fmaxf(z, 0.0f);
  __syncthreads();
  if (t < 40) {
    float z2 = bt2[t];
    for (int j = 0; j < 256; ++j) z2 += h1sh[j] * Wt2[(size_t)j*40 + t];
    out[(size_t)b*40 + t] = z2;
  }
}

extern "C" void kernel_launch(void* const* d_in, const int* in_sizes, int n_in,
                              void* d_out, int out_size, void* d_ws, size_t ws_size,
                              hipStream_t stream) {
  const float* x   = (const float*)d_in[0];
  // d_in[1] = batch indices (unused: equal-sized clouds)
  const float* W1  = (const float*)d_in[2];
  const float* B1  = (const float*)d_in[3];
  const float* W2  = (const float*)d_in[4];
  const float* B2  = (const float*)d_in[5];
  const float* W3  = (const float*)d_in[6];
  const float* B3  = (const float*)d_in[7];
  const float* W4  = (const float*)d_in[8];
  const float* B4  = (const float*)d_in[9];
  const float* Wp  = (const float*)d_in[10];
  const float* bp  = (const float*)d_in[11];
  const float* Wt1 = (const float*)d_in[12];
  const float* bt1 = (const float*)d_in[13];
  const float* Wt2 = (const float*)d_in[14];
  const float* bt2 = (const float*)d_in[15];
  float* out = (float*)d_out;

  // workspace layout (bytes, 256-aligned)
  char* ws = (char*)d_ws;
  const size_t OFF_SQ     = 0;           //  32768*4      = 131072
  const size_t OFF_IDX1   = 131072;      //  32768*20*4   = 2621440
  const size_t OFF_OUT1   = 2752512;     //  32768*64*4   = 8388608
  const size_t OFF_IDX2   = 11141120;    //  32768*20*4   = 2621440
  const size_t OFF_OUT2   = 13762560;    //  32768*128*4  = 16777216
  const size_t OFF_POOLED = 30539776;    //  32*512*4     = 65536
  const size_t WS_NEEDED  = 30605312;
  if (ws_size < WS_NEEDED) return;       // fail loudly (validation will catch it)

  float* sqbuf  = (float*)(ws + OFF_SQ);
  int*   idx1   = (int*)  (ws + OFF_IDX1);
  float* out1   = (float*)(ws + OFF_OUT1);
  int*   idx2   = (int*)  (ws + OFF_IDX2);
  float* out2   = (float*)(ws + OFF_OUT2);
  float* pooled = (float*)(ws + OFF_POOLED);
  // hi/lo bf16 split arrays alias the out2 region (4 MB each; out2 is 16.7 MB and is
  // only written by edge2_mfma AFTER knn64_mfma has consumed hi/lo — same stream).
  unsigned short* hib = (unsigned short*)(ws + OFF_OUT2);
  unsigned short* lob = (unsigned short*)(ws + OFF_OUT2 + 4194304);

  knn3_kernel      <<<NROWS/4,     256, 0, stream>>>(x, idx1);
  edge1_mfma_kernel<<<NROWS/4,     256, 0, stream>>>(x, idx1, W1, B1, W2, B2, W3, B3,
                                                     out1, hib, lob, sqbuf);
  knn64_mfma_kernel<<<NROWS/16,    1024, 0, stream>>>(hib, lob, sqbuf, idx2);
  edge2_mfma_kernel<<<NROWS/4,     256, 0, stream>>>(out1, idx2, W4, B4, out2);
  hipMemsetAsync(pooled, 0, NB*512*sizeof(float), stream);
  pool_kernel      <<<NB*8,        512, 0, stream>>>(out2, Wp, bp, pooled);
  head_kernel      <<<NB,          256, 0, stream>>>(pooled, Wt1, bt1, Wt2, bt2, out);
}

// Round 5
// 661.641 us; speedup vs baseline: 2.7296x; 1.0553x over previous
//
#include <hip/hip_runtime.h>
#include <math.h>

#define BN   1024
#define NB   32
#define KNN  20
#define NROWS (NB*BN)

typedef __attribute__((ext_vector_type(8))) short bf16x8_t;   // 8 bf16 (4 VGPRs)
typedef __attribute__((ext_vector_type(4))) float f32x4_t;    // MFMA accumulator

__device__ __forceinline__ float finf() { return __builtin_huge_valf(); }

__device__ __forceinline__ unsigned short f2bf(float f) {     // RTNE f32 -> bf16 bits
  union { float f; unsigned u; } v; v.f = f;
  unsigned r = v.u + 0x7FFFu + ((v.u >> 16) & 1u);
  return (unsigned short)(r >> 16);
}
__device__ __forceinline__ float bf2f(unsigned short h) {
  union { unsigned u; float f; } v; v.u = ((unsigned)h) << 16; return v.f;
}

// Select the 20 smallest of 1024 distances held wave-wide as dist[t] = d(row, j=t*64+lane).
// Tie-break: smaller j wins (matches jax.lax.top_k stability). All lanes agree after butterfly.
__device__ __forceinline__ void select20(float (&dist)[16], int lane, int* __restrict__ idx_out) {
  for (int e = 0; e < KNN; ++e) {
    float bd = dist[0]; int bt = 0;
#pragma unroll
    for (int t = 1; t < 16; ++t) { if (dist[t] < bd) { bd = dist[t]; bt = t; } }
    int bj = (bt << 6) | lane;
#pragma unroll
    for (int off = 32; off >= 1; off >>= 1) {
      float od = __shfl_xor(bd, off, 64);
      int   oj = __shfl_xor(bj, off, 64);
      if (od < bd || (od == bd && oj < bj)) { bd = od; bj = oj; }
    }
    if (lane == 0) idx_out[e] = bj;
    if ((bj & 63) == lane) {                 // owning lane invalidates (constant-indexed: rule #20)
      int tt = bj >> 6;
#pragma unroll
      for (int t = 0; t < 16; ++t) { if (t == tt) dist[t] = finf(); }
    }
  }
}

// ---------------- kNN on 3-D coords: one wave per row ----------------
__global__ __launch_bounds__(256) void knn3_kernel(const float* __restrict__ x, int* __restrict__ idxo) {
  const int wave = blockIdx.x * 4 + (threadIdx.x >> 6);
  const int lane = threadIdx.x & 63;
  const int b = wave >> 10, i = wave & (BN - 1);
  const float* xb = x + (size_t)b * BN * 3;
  const float xi0 = xb[i*3+0], xi1 = xb[i*3+1], xi2 = xb[i*3+2];
  const float sqi = xi0*xi0 + xi1*xi1 + xi2*xi2;
  float dist[16];
#pragma unroll
  for (int t = 0; t < 16; ++t) {
    const int j = (t << 6) | lane;
    const float a0 = xb[j*3+0], a1 = xb[j*3+1], a2 = xb[j*3+2];
    const float sqj = a0*a0 + a1*a1 + a2*a2;
    const float dt  = xi0*a0 + xi1*a1 + xi2*a2;
    const float d   = sqi + sqj - 2.0f*dt;        // reference formula
    dist[t] = (j == i) ? finf() : d;
  }
  select20(dist, lane, idxo + (size_t)wave * KNN);
}

// ---------------- EdgeConv1 via MFMA, register epilogue ----------------
// Block = 4 nodes x 20 edges = 80 rows, 4 waves. Layer1 (K=6) on VALU into swizzled
// bf16 LDS; layers 2,3 via mfma_16x16x32_bf16 (wave w owns n-tile w). Epilogue is
// in-register: per-lane node-max select + shfl butterfly across lane-groups; fuses
// max->out1, bf16 hi/lo split, and sqnorm (16-lane butterfly + LDS partials).
__global__ __launch_bounds__(256) void edge1_mfma_kernel(const float* __restrict__ x, const int* __restrict__ idx,
    const float* __restrict__ W1, const float* __restrict__ B1,
    const float* __restrict__ W2, const float* __restrict__ B2,
    const float* __restrict__ W3, const float* __restrict__ B3,
    float* __restrict__ out1, unsigned short* __restrict__ hib,
    unsigned short* __restrict__ lob, float* __restrict__ sqbuf) {
  __shared__ unsigned short Hs1[80*64];   // 10 KB, swizzled: [r][(c>>3)^(r&7)][c&7]
  __shared__ unsigned short Hs2[80*64];   // 10 KB
  __shared__ float part[4][4];            // sqnorm partials [node][wave]
  const int t = threadIdx.x, lane = t & 63, w = t >> 6;
  const int node0 = blockIdx.x * 4;

  // --- B fragments for layers 2 and 3: col = w*16+(lane&15), k = ks*32+(lane>>4)*8+e
  const int bcol  = w*16 + (lane & 15);
  const int krow0 = (lane >> 4) * 8;
  bf16x8_t Bf2[2], Bf3[2];
#pragma unroll
  for (int ks = 0; ks < 2; ++ks) {
#pragma unroll
    for (int e = 0; e < 8; ++e) {
      const int k = ks*32 + krow0 + e;
      Bf2[ks][e] = (short)f2bf(W2[(size_t)k*64 + bcol]);
      Bf3[ks][e] = (short)f2bf(W3[(size_t)k*64 + bcol]);
    }
  }

  // --- Layer 1 on VALU: lane = channel, 20 rows per wave
  float w1c[6];
#pragma unroll
  for (int c = 0; c < 6; ++c) w1c[c] = W1[c*64 + lane];
  const float b1o = B1[lane];
  for (int r = w; r < 80; r += 4) {
    const int g = (r * 205) >> 12;          // r/20 for r<80
    const int e = r - g*20;
    const int node = node0 + g;
    const int b = node >> 10;
    const int j = idx[(size_t)node*KNN + e];
    const float xi0 = x[(size_t)node*3+0], xi1 = x[(size_t)node*3+1], xi2 = x[(size_t)node*3+2];
    const size_t jr = ((size_t)(b*BN + j))*3;
    const float h3 = x[jr+0]-xi0, h4 = x[jr+1]-xi1, h5 = x[jr+2]-xi2;
    float z = b1o + xi0*w1c[0] + xi1*w1c[1] + xi2*w1c[2]
                  + h3*w1c[3] + h4*w1c[4] + h5*w1c[5];
    z = fmaxf(z, 0.0f);
    Hs1[r*64 + (((lane>>3) ^ (r&7))<<3) + (lane&7)] = f2bf(z);
  }
  __syncthreads();

  // --- Layer 2 MFMA: acc[mt] over 5 m-tiles, K=64 (2 k-steps)
  f32x4_t acc[5];
#pragma unroll
  for (int mt = 0; mt < 5; ++mt) acc[mt] = (f32x4_t){0,0,0,0};
#pragma unroll
  for (int ks = 0; ks < 2; ++ks) {
#pragma unroll
    for (int mt = 0; mt < 5; ++mt) {
      const int r = mt*16 + (lane & 15);
      const int chunk = ks*4 + (lane >> 4);          // k/8
      const bf16x8_t a = *(const bf16x8_t*)&Hs1[r*64 + ((chunk ^ (r&7))<<3)];
      acc[mt] = __builtin_amdgcn_mfma_f32_16x16x32_bf16(a, Bf2[ks], acc[mt], 0,0,0);
    }
  }
  // bias+relu -> bf16 -> Hs2 (C/D: col=lane&15 within tile, row=(lane>>4)*4+reg — m89)
  {
    const float b2o = B2[bcol];
    const int rbase = (lane >> 4) * 4;
#pragma unroll
    for (int mt = 0; mt < 5; ++mt) {
#pragma unroll
      for (int reg = 0; reg < 4; ++reg) {
        const int row = mt*16 + rbase + reg;
        const float v = fmaxf(acc[mt][reg] + b2o, 0.0f);
        Hs2[row*64 + (((bcol>>3) ^ (row&7))<<3) + (bcol&7)] = f2bf(v);
      }
    }
  }
  __syncthreads();

  // --- Layer 3 MFMA
#pragma unroll
  for (int mt = 0; mt < 5; ++mt) acc[mt] = (f32x4_t){0,0,0,0};
#pragma unroll
  for (int ks = 0; ks < 2; ++ks) {
#pragma unroll
    for (int mt = 0; mt < 5; ++mt) {
      const int r = mt*16 + (lane & 15);
      const int chunk = ks*4 + (lane >> 4);
      const bf16x8_t a = *(const bf16x8_t*)&Hs2[r*64 + ((chunk ^ (r&7))<<3)];
      acc[mt] = __builtin_amdgcn_mfma_f32_16x16x32_bf16(a, Bf3[ks], acc[mt], 0,0,0);
    }
  }

  // --- Register epilogue: bias+relu, per-node max (select trick, relu=>0 identity),
  //     butterfly across lane-groups (rows), then group g stores node g.
  {
    const float b3o = B3[bcol];
    const int rbase = (lane >> 4) * 4;
    float nm0 = 0.0f, nm1 = 0.0f, nm2 = 0.0f, nm3 = 0.0f;
#pragma unroll
    for (int mt = 0; mt < 5; ++mt) {
#pragma unroll
      for (int reg = 0; reg < 4; ++reg) {
        const int r = mt*16 + rbase + reg;
        const int g = (r * 205) >> 12;
        const float v = fmaxf(acc[mt][reg] + b3o, 0.0f);
        nm0 = (g == 0) ? fmaxf(nm0, v) : nm0;
        nm1 = (g == 1) ? fmaxf(nm1, v) : nm1;
        nm2 = (g == 2) ? fmaxf(nm2, v) : nm2;
        nm3 = (g == 3) ? fmaxf(nm3, v) : nm3;
      }
    }
#pragma unroll
    for (int off = 16; off <= 32; off <<= 1) {
      nm0 = fmaxf(nm0, __shfl_xor(nm0, off, 64));
      nm1 = fmaxf(nm1, __shfl_xor(nm1, off, 64));
      nm2 = fmaxf(nm2, __shfl_xor(nm2, off, 64));
      nm3 = fmaxf(nm3, __shfl_xor(nm3, off, 64));
    }
    const int gq = lane >> 4;
    const float m = (gq == 0) ? nm0 : (gq == 1) ? nm1 : (gq == 2) ? nm2 : nm3;
    const int node = node0 + gq;
    out1[(size_t)node*64 + bcol] = m;
    const unsigned short h = f2bf(m);
    hib[(size_t)node*64 + bcol] = h;
    lob[(size_t)node*64 + bcol] = f2bf(m - bf2f(h));
    float s = m * m;                       // sqnorm partial over this group's 16 cols
#pragma unroll
    for (int off = 1; off <= 8; off <<= 1) s += __shfl_xor(s, off, 64);
    if ((lane & 15) == 0) part[gq][w] = s;
  }
  __syncthreads();
  if (t < 4) sqbuf[node0 + t] = part[t][0] + part[t][1] + part[t][2] + part[t][3];
}

// ---------------- kNN on 64-d features via bf16x3 MFMA ----------------
__global__ __launch_bounds__(1024) void knn64_mfma_kernel(
    const unsigned short* __restrict__ hi, const unsigned short* __restrict__ lo,
    const float* __restrict__ sq, int* __restrict__ idxo) {
  __shared__ float Dmat[16 * 1024];                 // 64 KiB
  const int t = threadIdx.x, lane = t & 63, w = t >> 6;   // w in [0,16)
  const int i0  = blockIdx.x * 16;                  // global row base (blocks never straddle a batch)
  const int b   = i0 >> 10;
  const int i0l = i0 & (BN - 1);

  const size_t arow = (size_t)(i0 + (lane & 15)) * 64;
  const int    koff = (lane >> 4) * 8;
  bf16x8_t Ahi[2], Alo[2];
#pragma unroll
  for (int ks = 0; ks < 2; ++ks) {
    Ahi[ks] = *(const bf16x8_t*)&hi[arow + ks*32 + koff];
    Alo[ks] = *(const bf16x8_t*)&lo[arow + ks*32 + koff];
  }

  f32x4_t acc[4];
#pragma unroll
  for (int nt = 0; nt < 4; ++nt) {
    const int jl = (4*w + nt)*16 + (lane & 15);     // B col -> local node j
    const size_t jrow = ((size_t)(b << 10) + jl) * 64;
    const bf16x8_t Bhi0 = *(const bf16x8_t*)&hi[jrow + koff];
    const bf16x8_t Bhi1 = *(const bf16x8_t*)&hi[jrow + 32 + koff];
    const bf16x8_t Blo0 = *(const bf16x8_t*)&lo[jrow + koff];
    const bf16x8_t Blo1 = *(const bf16x8_t*)&lo[jrow + 32 + koff];
    f32x4_t a = (f32x4_t){0,0,0,0};
    a = __builtin_amdgcn_mfma_f32_16x16x32_bf16(Ahi[0], Bhi0, a, 0,0,0);
    a = __builtin_amdgcn_mfma_f32_16x16x32_bf16(Ahi[1], Bhi1, a, 0,0,0);
    a = __builtin_amdgcn_mfma_f32_16x16x32_bf16(Ahi[0], Blo0, a, 0,0,0);
    a = __builtin_amdgcn_mfma_f32_16x16x32_bf16(Ahi[1], Blo1, a, 0,0,0);
    a = __builtin_amdgcn_mfma_f32_16x16x32_bf16(Alo[0], Bhi0, a, 0,0,0);
    a = __builtin_amdgcn_mfma_f32_16x16x32_bf16(Alo[1], Bhi1, a, 0,0,0);
    acc[nt] = a;
  }

  const int rbase = (lane >> 4) * 4;
  float sqr[4];
#pragma unroll
  for (int r = 0; r < 4; ++r) sqr[r] = sq[i0 + rbase + r];
#pragma unroll
  for (int nt = 0; nt < 4; ++nt) {
    const int jl = (4*w + nt)*16 + (lane & 15);
    const float sqj = sq[(b << 10) + jl];
#pragma unroll
    for (int r = 0; r < 4; ++r) {
      float d = sqr[r] + sqj - 2.0f * acc[nt][r];
      if (jl == i0l + rbase + r) d = finf();        // exclude self
      Dmat[(rbase + r)*1024 + jl] = d;
    }
  }
  __syncthreads();

  float dist[16];
#pragma unroll
  for (int tt = 0; tt < 16; ++tt) dist[tt] = Dmat[w*1024 + tt*64 + lane];  // 2-way: free
  select20(dist, lane, idxo + (size_t)(i0 + w) * KNN);
}

// ---------------- EdgeConv2 as bf16 MFMA GEMM, register epilogue ----------------
// Block = 4 nodes x 20 edges = 80 rows = 5 M-tiles. K=128, N=128 (wave w owns n-tiles
// {2w,2w+1}). One barrier; max over 20 edges done in registers + shfl butterfly.
__global__ __launch_bounds__(256) void edge2_mfma_kernel(const float* __restrict__ f, const int* __restrict__ idx,
    const float* __restrict__ W4, const float* __restrict__ B4, float* __restrict__ out2) {
  __shared__ unsigned short Hs[80*128];   // 20 KB bf16, swizzled: [r][chunk^(r&7)][0..7]
  const int t = threadIdx.x, lane = t & 63, w = t >> 6;
  const int node0 = blockIdx.x * 4;

  bf16x8_t Bfrag[2][4];
  const int bcol  = lane & 15;
  const int krow0 = (lane >> 4) * 8;
#pragma unroll
  for (int nti = 0; nti < 2; ++nti) {
    const int nt = 2*w + nti;
#pragma unroll
    for (int ks = 0; ks < 4; ++ks) {
#pragma unroll
      for (int e = 0; e < 8; ++e) {
        const int k = ks*32 + krow0 + e;
        Bfrag[nti][ks][e] = (short)f2bf(W4[(size_t)k*128 + nt*16 + bcol]);
      }
    }
  }

  for (int r = w; r < 80; r += 4) {
    const int g = (r * 205) >> 12;          // r/20 for r<80
    const int e = r - g*20;
    const int node = node0 + g;
    const int b = node >> 10;
    const int j = idx[(size_t)node*KNN + e];
    const float xi = f[(size_t)node*64 + lane];
    const float xj = f[((size_t)(b*BN + j))*64 + lane];
    const int c1 = lane, c2 = 64 + lane;
    Hs[r*128 + (((c1>>3) ^ (r&7))<<3) + (c1&7)] = f2bf(xi);
    Hs[r*128 + (((c2>>3) ^ (r&7))<<3) + (c2&7)] = f2bf(xj - xi);
  }
  __syncthreads();

  f32x4_t acc[5][2];
#pragma unroll
  for (int mt = 0; mt < 5; ++mt) { acc[mt][0] = (f32x4_t){0,0,0,0}; acc[mt][1] = (f32x4_t){0,0,0,0}; }
#pragma unroll
  for (int ks = 0; ks < 4; ++ks) {
#pragma unroll
    for (int mt = 0; mt < 5; ++mt) {
      const int r = mt*16 + (lane & 15);
      const int chunk = ks*4 + (lane >> 4);
      const bf16x8_t a = *(const bf16x8_t*)&Hs[r*128 + ((chunk ^ (r&7))<<3)];
      acc[mt][0] = __builtin_amdgcn_mfma_f32_16x16x32_bf16(a, Bfrag[0][ks], acc[mt][0], 0,0,0);
      acc[mt][1] = __builtin_amdgcn_mfma_f32_16x16x32_bf16(a, Bfrag[1][ks], acc[mt][1], 0,0,0);
    }
  }

  // --- Register epilogue (C/D: col=lane&15, row=(lane>>4)*4+reg — m89):
  //     bias+relu, select-accumulate per-node maxes, butterfly across lane-groups,
  //     group gq stores node gq. No Zs, no second barrier.
  const float bb0 = B4[(2*w+0)*16 + bcol];
  const float bb1 = B4[(2*w+1)*16 + bcol];
  const int rbase = (lane >> 4) * 4;
  float nm0[2] = {0,0}, nm1[2] = {0,0}, nm2[2] = {0,0}, nm3[2] = {0,0};
#pragma unroll
  for (int mt = 0; mt < 5; ++mt) {
#pragma unroll
    for (int reg = 0; reg < 4; ++reg) {
      const int r = mt*16 + rbase + reg;
      const int g = (r * 205) >> 12;
      const float v0 = fmaxf(acc[mt][0][reg] + bb0, 0.0f);
      const float v1 = fmaxf(acc[mt][1][reg] + bb1, 0.0f);
      nm0[0] = (g == 0) ? fmaxf(nm0[0], v0) : nm0[0];
      nm1[0] = (g == 1) ? fmaxf(nm1[0], v0) : nm1[0];
      nm2[0] = (g == 2) ? fmaxf(nm2[0], v0) : nm2[0];
      nm3[0] = (g == 3) ? fmaxf(nm3[0], v0) : nm3[0];
      nm0[1] = (g == 0) ? fmaxf(nm0[1], v1) : nm0[1];
      nm1[1] = (g == 1) ? fmaxf(nm1[1], v1) : nm1[1];
      nm2[1] = (g == 2) ? fmaxf(nm2[1], v1) : nm2[1];
      nm3[1] = (g == 3) ? fmaxf(nm3[1], v1) : nm3[1];
    }
  }
#pragma unroll
  for (int off = 16; off <= 32; off <<= 1) {
#pragma unroll
    for (int nti = 0; nti < 2; ++nti) {
      nm0[nti] = fmaxf(nm0[nti], __shfl_xor(nm0[nti], off, 64));
      nm1[nti] = fmaxf(nm1[nti], __shfl_xor(nm1[nti], off, 64));
      nm2[nti] = fmaxf(nm2[nti], __shfl_xor(nm2[nti], off, 64));
      nm3[nti] = fmaxf(nm3[nti], __shfl_xor(nm3[nti], off, 64));
    }
  }
  const int gq = lane >> 4;
#pragma unroll
  for (int nti = 0; nti < 2; ++nti) {
    const float m = (gq == 0) ? nm0[nti] : (gq == 1) ? nm1[nti] : (gq == 2) ? nm2[nti] : nm3[nti];
    out2[(size_t)(node0 + gq)*128 + (2*w + nti)*16 + bcol] = m;
  }
}

// ---------------- 128->512 pointwise + global max pool (fused, atomicMax on relu'd values) ---------
__global__ __launch_bounds__(512) void pool_kernel(const float* __restrict__ f, const float* __restrict__ Wp,
    const float* __restrict__ bp, float* __restrict__ pooled) {
  __shared__ float xsh[128];
  const int o = threadIdx.x;
  const int b = blockIdx.x >> 3, chunk = blockIdx.x & 7;
  float wc[128];
#pragma unroll
  for (int c = 0; c < 128; ++c) wc[c] = Wp[(size_t)c*512 + o];
  const float bo = bp[o];
  float m = -finf();
  for (int n = chunk * 128; n < chunk * 128 + 128; ++n) {
    if (o < 128) xsh[o] = f[((size_t)b*BN + n)*128 + o];
    __syncthreads();
    float z = bo;
    const float4* p = (const float4*)xsh;
#pragma unroll
    for (int c = 0; c < 32; ++c) {
      const float4 v = p[c];
      z += v.x*wc[4*c+0] + v.y*wc[4*c+1] + v.z*wc[4*c+2] + v.w*wc[4*c+3];
    }
    m = fmaxf(m, z);
    __syncthreads();
  }
  m = fmaxf(m, 0.0f);   // relu(max z) == max relu(z); non-negative -> int-bit atomicMax is order-correct
  atomicMax((int*)(pooled + (size_t)b*512 + o), __float_as_int(m));
}

// ---------------- classifier head 512->256(relu)->40 ----------------
__global__ __launch_bounds__(256) void head_kernel(const float* __restrict__ pooled,
    const float* __restrict__ Wt1, const float* __restrict__ bt1,
    const float* __restrict__ Wt2, const float* __restrict__ bt2,
    float* __restrict__ out) {
  __shared__ float psh[512];
  __shared__ float h1sh[256];
  const int t = threadIdx.x, b = blockIdx.x;
  psh[t]       = pooled[(size_t)b*512 + t];
  psh[t + 256] = pooled[(size_t)b*512 + t + 256];
  __syncthreads();
  float z = bt1[t];
  for (int j = 0; j < 512; ++j) z += psh[j] * Wt1[(size_t)j*256 + t];
  h1sh[t] = fmaxf(z, 0.0f);
  __syncthreads();
  if (t < 40) {
    float z2 = bt2[t];
    for (int j = 0; j < 256; ++j) z2 += h1sh[j] * Wt2[(size_t)j*40 + t];
    out[(size_t)b*40 + t] = z2;
  }
}

extern "C" void kernel_launch(void* const* d_in, const int* in_sizes, int n_in,
                              void* d_out, int out_size, void* d_ws, size_t ws_size,
                              hipStream_t stream) {
  const float* x   = (const float*)d_in[0];
  // d_in[1] = batch indices (unused: equal-sized clouds)
  const float* W1  = (const float*)d_in[2];
  const float* B1  = (const float*)d_in[3];
  const float* W2  = (const float*)d_in[4];
  const float* B2  = (const float*)d_in[5];
  const float* W3  = (const float*)d_in[6];
  const float* B3  = (const float*)d_in[7];
  const float* W4  = (const float*)d_in[8];
  const float* B4  = (const float*)d_in[9];
  const float* Wp  = (const float*)d_in[10];
  const float* bp  = (const float*)d_in[11];
  const float* Wt1 = (const float*)d_in[12];
  const float* bt1 = (const float*)d_in[13];
  const float* Wt2 = (const float*)d_in[14];
  const float* bt2 = (const float*)d_in[15];
  float* out = (float*)d_out;

  // workspace layout (bytes, 256-aligned)
  char* ws = (char*)d_ws;
  const size_t OFF_SQ     = 0;           //  32768*4      = 131072
  const size_t OFF_IDX1   = 131072;      //  32768*20*4   = 2621440
  const size_t OFF_OUT1   = 2752512;     //  32768*64*4   = 8388608
  const size_t OFF_IDX2   = 11141120;    //  32768*20*4   = 2621440
  const size_t OFF_OUT2   = 13762560;    //  32768*128*4  = 16777216
  const size_t OFF_POOLED = 30539776;    //  32*512*4     = 65536
  const size_t WS_NEEDED  = 30605312;
  if (ws_size < WS_NEEDED) return;       // fail loudly (validation will catch it)

  float* sqbuf  = (float*)(ws + OFF_SQ);
  int*   idx1   = (int*)  (ws + OFF_IDX1);
  float* out1   = (float*)(ws + OFF_OUT1);
  int*   idx2   = (int*)  (ws + OFF_IDX2);
  float* out2   = (float*)(ws + OFF_OUT2);
  float* pooled = (float*)(ws + OFF_POOLED);
  // hi/lo bf16 split arrays alias the out2 region (4 MB each; out2 is 16.7 MB and is
  // only written by edge2_mfma AFTER knn64_mfma has consumed hi/lo — same stream).
  unsigned short* hib = (unsigned short*)(ws + OFF_OUT2);
  unsigned short* lob = (unsigned short*)(ws + OFF_OUT2 + 4194304);

  knn3_kernel      <<<NROWS/4,     256, 0, stream>>>(x, idx1);
  edge1_mfma_kernel<<<NROWS/4,     256, 0, stream>>>(x, idx1, W1, B1, W2, B2, W3, B3,
                                                     out1, hib, lob, sqbuf);
  knn64_mfma_kernel<<<NROWS/16,    1024, 0, stream>>>(hib, lob, sqbuf, idx2);
  edge2_mfma_kernel<<<NROWS/4,     256, 0, stream>>>(out1, idx2, W4, B4, out2);
  hipMemsetAsync(pooled, 0, NB*512*sizeof(float), stream);
  pool_kernel      <<<NB*8,        512, 0, stream>>>(out2, Wp, bp, pooled);
  head_kernel      <<<NB,          256, 0, stream>>>(pooled, Wt1, bt1, Wt2, bt2, out);
}

// Round 6
// 590.815 us; speedup vs baseline: 3.0568x; 1.1199x over previous
//
#include <hip/hip_runtime.h>
#include <math.h>

#define BN   1024
#define NB   32
#define KNN  20
#define NROWS (NB*BN)

typedef __attribute__((ext_vector_type(8))) short bf16x8_t;   // 8 bf16 (4 VGPRs)
typedef __attribute__((ext_vector_type(4))) float f32x4_t;    // MFMA accumulator

__device__ __forceinline__ float finf() { return __builtin_huge_valf(); }

__device__ __forceinline__ unsigned short f2bf(float f) {     // RTNE f32 -> bf16 bits
  union { float f; unsigned u; } v; v.f = f;
  unsigned r = v.u + 0x7FFFu + ((v.u >> 16) & 1u);
  return (unsigned short)(r >> 16);
}
__device__ __forceinline__ float bf2f(unsigned short h) {
  union { unsigned u; float f; } v; v.u = ((unsigned)h) << 16; return v.f;
}

// Monotone float -> uint transform: unsigned order == float order (handles negatives).
__device__ __forceinline__ unsigned fkey(float d) {
  union { float f; unsigned u; } v; v.f = d;
  return (v.u & 0x80000000u) ? ~v.u : (v.u | 0x80000000u);
}

// Packed-key select: kq[t] = (fkey(d) & ~1023) | j for j = t*64+lane. 20 smallest by
// (quantized d, then smaller j) — ties at 2^-13 relative resolved by index; max-over-k
// downstream is permutation-invariant so only 20/21 boundary membership matters.
// Keys are globally unique (j embedded) so invalidation is an equality compare.
__device__ __forceinline__ void select20p(unsigned (&kq)[16], int lane, int* __restrict__ idx_out) {
  for (int e = 0; e < KNN; ++e) {
    unsigned m = kq[0];
#pragma unroll
    for (int t = 1; t < 16; ++t) m = (kq[t] < m) ? kq[t] : m;
#pragma unroll
    for (int off = 32; off >= 1; off >>= 1) {
      const unsigned o = (unsigned)__shfl_xor((int)m, off, 64);
      m = (o < m) ? o : m;
    }
    if (lane == 0) idx_out[e] = (int)(m & 1023u);
#pragma unroll
    for (int t = 0; t < 16; ++t) kq[t] = (kq[t] == m) ? 0xFFFFFFFFu : kq[t];
  }
}

// ---------------- kNN on 3-D coords: one wave per row, packed-key select ----------------
__global__ __launch_bounds__(256) void knn3_kernel(const float* __restrict__ x, int* __restrict__ idxo) {
  const int wave = blockIdx.x * 4 + (threadIdx.x >> 6);
  const int lane = threadIdx.x & 63;
  const int b = wave >> 10, i = wave & (BN - 1);
  const float* xb = x + (size_t)b * BN * 3;
  const float xi0 = xb[i*3+0], xi1 = xb[i*3+1], xi2 = xb[i*3+2];
  const float sqi = xi0*xi0 + xi1*xi1 + xi2*xi2;
  unsigned kq[16];
#pragma unroll
  for (int t = 0; t < 16; ++t) {
    const int j = (t << 6) | lane;
    const float a0 = xb[j*3+0], a1 = xb[j*3+1], a2 = xb[j*3+2];
    const float sqj = a0*a0 + a1*a1 + a2*a2;
    const float dt  = xi0*a0 + xi1*a1 + xi2*a2;
    const float d   = sqi + sqj - 2.0f*dt;        // reference formula
    kq[t] = (j == i) ? 0xFFFFFFFFu : ((fkey(d) & 0xFFFFFC00u) | (unsigned)j);
  }
  select20p(kq, lane, idxo + (size_t)wave * KNN);
}

// ---------------- EdgeConv1 via MFMA, register epilogue ----------------
__global__ __launch_bounds__(256) void edge1_mfma_kernel(const float* __restrict__ x, const int* __restrict__ idx,
    const float* __restrict__ W1, const float* __restrict__ B1,
    const float* __restrict__ W2, const float* __restrict__ B2,
    const float* __restrict__ W3, const float* __restrict__ B3,
    float* __restrict__ out1, unsigned short* __restrict__ hib,
    unsigned short* __restrict__ lob, float* __restrict__ sqbuf) {
  __shared__ unsigned short Hs1[80*64];   // 10 KB, swizzled: [r][(c>>3)^(r&7)][c&7]
  __shared__ unsigned short Hs2[80*64];   // 10 KB
  __shared__ float part[4][4];            // sqnorm partials [node][wave]
  const int t = threadIdx.x, lane = t & 63, w = t >> 6;
  const int node0 = blockIdx.x * 4;

  const int bcol  = w*16 + (lane & 15);
  const int krow0 = (lane >> 4) * 8;
  bf16x8_t Bf2[2], Bf3[2];
#pragma unroll
  for (int ks = 0; ks < 2; ++ks) {
#pragma unroll
    for (int e = 0; e < 8; ++e) {
      const int k = ks*32 + krow0 + e;
      Bf2[ks][e] = (short)f2bf(W2[(size_t)k*64 + bcol]);
      Bf3[ks][e] = (short)f2bf(W3[(size_t)k*64 + bcol]);
    }
  }

  float w1c[6];
#pragma unroll
  for (int c = 0; c < 6; ++c) w1c[c] = W1[c*64 + lane];
  const float b1o = B1[lane];
  for (int r = w; r < 80; r += 4) {
    const int g = (r * 205) >> 12;          // r/20 for r<80
    const int e = r - g*20;
    const int node = node0 + g;
    const int b = node >> 10;
    const int j = idx[(size_t)node*KNN + e];
    const float xi0 = x[(size_t)node*3+0], xi1 = x[(size_t)node*3+1], xi2 = x[(size_t)node*3+2];
    const size_t jr = ((size_t)(b*BN + j))*3;
    const float h3 = x[jr+0]-xi0, h4 = x[jr+1]-xi1, h5 = x[jr+2]-xi2;
    float z = b1o + xi0*w1c[0] + xi1*w1c[1] + xi2*w1c[2]
                  + h3*w1c[3] + h4*w1c[4] + h5*w1c[5];
    z = fmaxf(z, 0.0f);
    Hs1[r*64 + (((lane>>3) ^ (r&7))<<3) + (lane&7)] = f2bf(z);
  }
  __syncthreads();

  f32x4_t acc[5];
#pragma unroll
  for (int mt = 0; mt < 5; ++mt) acc[mt] = (f32x4_t){0,0,0,0};
#pragma unroll
  for (int ks = 0; ks < 2; ++ks) {
#pragma unroll
    for (int mt = 0; mt < 5; ++mt) {
      const int r = mt*16 + (lane & 15);
      const int chunk = ks*4 + (lane >> 4);          // k/8
      const bf16x8_t a = *(const bf16x8_t*)&Hs1[r*64 + ((chunk ^ (r&7))<<3)];
      acc[mt] = __builtin_amdgcn_mfma_f32_16x16x32_bf16(a, Bf2[ks], acc[mt], 0,0,0);
    }
  }
  {
    const float b2o = B2[bcol];
    const int rbase = (lane >> 4) * 4;
#pragma unroll
    for (int mt = 0; mt < 5; ++mt) {
#pragma unroll
      for (int reg = 0; reg < 4; ++reg) {
        const int row = mt*16 + rbase + reg;
        const float v = fmaxf(acc[mt][reg] + b2o, 0.0f);
        Hs2[row*64 + (((bcol>>3) ^ (row&7))<<3) + (bcol&7)] = f2bf(v);
      }
    }
  }
  __syncthreads();

#pragma unroll
  for (int mt = 0; mt < 5; ++mt) acc[mt] = (f32x4_t){0,0,0,0};
#pragma unroll
  for (int ks = 0; ks < 2; ++ks) {
#pragma unroll
    for (int mt = 0; mt < 5; ++mt) {
      const int r = mt*16 + (lane & 15);
      const int chunk = ks*4 + (lane >> 4);
      const bf16x8_t a = *(const bf16x8_t*)&Hs2[r*64 + ((chunk ^ (r&7))<<3)];
      acc[mt] = __builtin_amdgcn_mfma_f32_16x16x32_bf16(a, Bf3[ks], acc[mt], 0,0,0);
    }
  }

  {
    const float b3o = B3[bcol];
    const int rbase = (lane >> 4) * 4;
    float nm0 = 0.0f, nm1 = 0.0f, nm2 = 0.0f, nm3 = 0.0f;
#pragma unroll
    for (int mt = 0; mt < 5; ++mt) {
#pragma unroll
      for (int reg = 0; reg < 4; ++reg) {
        const int r = mt*16 + rbase + reg;
        const int g = (r * 205) >> 12;
        const float v = fmaxf(acc[mt][reg] + b3o, 0.0f);
        nm0 = (g == 0) ? fmaxf(nm0, v) : nm0;
        nm1 = (g == 1) ? fmaxf(nm1, v) : nm1;
        nm2 = (g == 2) ? fmaxf(nm2, v) : nm2;
        nm3 = (g == 3) ? fmaxf(nm3, v) : nm3;
      }
    }
#pragma unroll
    for (int off = 16; off <= 32; off <<= 1) {
      nm0 = fmaxf(nm0, __shfl_xor(nm0, off, 64));
      nm1 = fmaxf(nm1, __shfl_xor(nm1, off, 64));
      nm2 = fmaxf(nm2, __shfl_xor(nm2, off, 64));
      nm3 = fmaxf(nm3, __shfl_xor(nm3, off, 64));
    }
    const int gq = lane >> 4;
    const float m = (gq == 0) ? nm0 : (gq == 1) ? nm1 : (gq == 2) ? nm2 : nm3;
    const int node = node0 + gq;
    out1[(size_t)node*64 + bcol] = m;
    const unsigned short h = f2bf(m);
    hib[(size_t)node*64 + bcol] = h;
    lob[(size_t)node*64 + bcol] = f2bf(m - bf2f(h));
    float s = m * m;
#pragma unroll
    for (int off = 1; off <= 8; off <<= 1) s += __shfl_xor(s, off, 64);
    if ((lane & 15) == 0) part[gq][w] = s;
  }
  __syncthreads();
  if (t < 4) sqbuf[node0 + t] = part[t][0] + part[t][1] + part[t][2] + part[t][3];
}

// ---------------- kNN on 64-d features via bf16x3 MFMA + packed-key select ----------------
// Writer waves pack (quantized distance | column) keys straight into Dmat (uint).
__global__ __launch_bounds__(1024) void knn64_mfma_kernel(
    const unsigned short* __restrict__ hi, const unsigned short* __restrict__ lo,
    const float* __restrict__ sq, int* __restrict__ idxo) {
  __shared__ unsigned Dmat[16 * 1024];              // 64 KiB packed keys
  const int t = threadIdx.x, lane = t & 63, w = t >> 6;   // w in [0,16)
  const int i0  = blockIdx.x * 16;                  // global row base (blocks never straddle a batch)
  const int b   = i0 >> 10;
  const int i0l = i0 & (BN - 1);

  const size_t arow = (size_t)(i0 + (lane & 15)) * 64;
  const int    koff = (lane >> 4) * 8;
  bf16x8_t Ahi[2], Alo[2];
#pragma unroll
  for (int ks = 0; ks < 2; ++ks) {
    Ahi[ks] = *(const bf16x8_t*)&hi[arow + ks*32 + koff];
    Alo[ks] = *(const bf16x8_t*)&lo[arow + ks*32 + koff];
  }

  f32x4_t acc[4];
#pragma unroll
  for (int nt = 0; nt < 4; ++nt) {
    const int jl = (4*w + nt)*16 + (lane & 15);     // B col -> local node j
    const size_t jrow = ((size_t)(b << 10) + jl) * 64;
    const bf16x8_t Bhi0 = *(const bf16x8_t*)&hi[jrow + koff];
    const bf16x8_t Bhi1 = *(const bf16x8_t*)&hi[jrow + 32 + koff];
    const bf16x8_t Blo0 = *(const bf16x8_t*)&lo[jrow + koff];
    const bf16x8_t Blo1 = *(const bf16x8_t*)&lo[jrow + 32 + koff];
    f32x4_t a = (f32x4_t){0,0,0,0};
    a = __builtin_amdgcn_mfma_f32_16x16x32_bf16(Ahi[0], Bhi0, a, 0,0,0);
    a = __builtin_amdgcn_mfma_f32_16x16x32_bf16(Ahi[1], Bhi1, a, 0,0,0);
    a = __builtin_amdgcn_mfma_f32_16x16x32_bf16(Ahi[0], Blo0, a, 0,0,0);
    a = __builtin_amdgcn_mfma_f32_16x16x32_bf16(Ahi[1], Blo1, a, 0,0,0);
    a = __builtin_amdgcn_mfma_f32_16x16x32_bf16(Alo[0], Bhi0, a, 0,0,0);
    a = __builtin_amdgcn_mfma_f32_16x16x32_bf16(Alo[1], Bhi1, a, 0,0,0);
    acc[nt] = a;
  }

  const int rbase = (lane >> 4) * 4;
  float sqr[4];
#pragma unroll
  for (int r = 0; r < 4; ++r) sqr[r] = sq[i0 + rbase + r];
#pragma unroll
  for (int nt = 0; nt < 4; ++nt) {
    const int jl = (4*w + nt)*16 + (lane & 15);
    const float sqj = sq[(b << 10) + jl];
#pragma unroll
    for (int r = 0; r < 4; ++r) {
      const float d = sqr[r] + sqj - 2.0f * acc[nt][r];
      const unsigned kq = (jl == i0l + rbase + r) ? 0xFFFFFFFFu
                        : ((fkey(d) & 0xFFFFFC00u) | (unsigned)jl);
      Dmat[(rbase + r)*1024 + jl] = kq;
    }
  }
  __syncthreads();

  unsigned kq[16];
#pragma unroll
  for (int tt = 0; tt < 16; ++tt) kq[tt] = Dmat[w*1024 + tt*64 + lane];  // 2-way: free
  select20p(kq, lane, idxo + (size_t)(i0 + w) * KNN);
}

// ---------------- EdgeConv2 as bf16 MFMA GEMM, register epilogue ----------------
__global__ __launch_bounds__(256) void edge2_mfma_kernel(const float* __restrict__ f, const int* __restrict__ idx,
    const float* __restrict__ W4, const float* __restrict__ B4, float* __restrict__ out2) {
  __shared__ unsigned short Hs[80*128];   // 20 KB bf16, swizzled: [r][chunk^(r&7)][0..7]
  const int t = threadIdx.x, lane = t & 63, w = t >> 6;
  const int node0 = blockIdx.x * 4;

  bf16x8_t Bfrag[2][4];
  const int bcol  = lane & 15;
  const int krow0 = (lane >> 4) * 8;
#pragma unroll
  for (int nti = 0; nti < 2; ++nti) {
    const int nt = 2*w + nti;
#pragma unroll
    for (int ks = 0; ks < 4; ++ks) {
#pragma unroll
      for (int e = 0; e < 8; ++e) {
        const int k = ks*32 + krow0 + e;
        Bfrag[nti][ks][e] = (short)f2bf(W4[(size_t)k*128 + nt*16 + bcol]);
      }
    }
  }

  for (int r = w; r < 80; r += 4) {
    const int g = (r * 205) >> 12;          // r/20 for r<80
    const int e = r - g*20;
    const int node = node0 + g;
    const int b = node >> 10;
    const int j = idx[(size_t)node*KNN + e];
    const float xi = f[(size_t)node*64 + lane];
    const float xj = f[((size_t)(b*BN + j))*64 + lane];
    const int c1 = lane, c2 = 64 + lane;
    Hs[r*128 + (((c1>>3) ^ (r&7))<<3) + (c1&7)] = f2bf(xi);
    Hs[r*128 + (((c2>>3) ^ (r&7))<<3) + (c2&7)] = f2bf(xj - xi);
  }
  __syncthreads();

  f32x4_t acc[5][2];
#pragma unroll
  for (int mt = 0; mt < 5; ++mt) { acc[mt][0] = (f32x4_t){0,0,0,0}; acc[mt][1] = (f32x4_t){0,0,0,0}; }
#pragma unroll
  for (int ks = 0; ks < 4; ++ks) {
#pragma unroll
    for (int mt = 0; mt < 5; ++mt) {
      const int r = mt*16 + (lane & 15);
      const int chunk = ks*4 + (lane >> 4);
      const bf16x8_t a = *(const bf16x8_t*)&Hs[r*128 + ((chunk ^ (r&7))<<3)];
      acc[mt][0] = __builtin_amdgcn_mfma_f32_16x16x32_bf16(a, Bfrag[0][ks], acc[mt][0], 0,0,0);
      acc[mt][1] = __builtin_amdgcn_mfma_f32_16x16x32_bf16(a, Bfrag[1][ks], acc[mt][1], 0,0,0);
    }
  }

  const float bb0 = B4[(2*w+0)*16 + bcol];
  const float bb1 = B4[(2*w+1)*16 + bcol];
  const int rbase = (lane >> 4) * 4;
  float nm0[2] = {0,0}, nm1[2] = {0,0}, nm2[2] = {0,0}, nm3[2] = {0,0};
#pragma unroll
  for (int mt = 0; mt < 5; ++mt) {
#pragma unroll
    for (int reg = 0; reg < 4; ++reg) {
      const int r = mt*16 + rbase + reg;
      const int g = (r * 205) >> 12;
      const float v0 = fmaxf(acc[mt][0][reg] + bb0, 0.0f);
      const float v1 = fmaxf(acc[mt][1][reg] + bb1, 0.0f);
      nm0[0] = (g == 0) ? fmaxf(nm0[0], v0) : nm0[0];
      nm1[0] = (g == 1) ? fmaxf(nm1[0], v0) : nm1[0];
      nm2[0] = (g == 2) ? fmaxf(nm2[0], v0) : nm2[0];
      nm3[0] = (g == 3) ? fmaxf(nm3[0], v0) : nm3[0];
      nm0[1] = (g == 0) ? fmaxf(nm0[1], v1) : nm0[1];
      nm1[1] = (g == 1) ? fmaxf(nm1[1], v1) : nm1[1];
      nm2[1] = (g == 2) ? fmaxf(nm2[1], v1) : nm2[1];
      nm3[1] = (g == 3) ? fmaxf(nm3[1], v1) : nm3[1];
    }
  }
#pragma unroll
  for (int off = 16; off <= 32; off <<= 1) {
#pragma unroll
    for (int nti = 0; nti < 2; ++nti) {
      nm0[nti] = fmaxf(nm0[nti], __shfl_xor(nm0[nti], off, 64));
      nm1[nti] = fmaxf(nm1[nti], __shfl_xor(nm1[nti], off, 64));
      nm2[nti] = fmaxf(nm2[nti], __shfl_xor(nm2[nti], off, 64));
      nm3[nti] = fmaxf(nm3[nti], __shfl_xor(nm3[nti], off, 64));
    }
  }
  const int gq = lane >> 4;
#pragma unroll
  for (int nti = 0; nti < 2; ++nti) {
    const float m = (gq == 0) ? nm0[nti] : (gq == 1) ? nm1[nti] : (gq == 2) ? nm2[nti] : nm3[nti];
    out2[(size_t)(node0 + gq)*128 + (2*w + nti)*16 + bcol] = m;
  }
}

// ---------------- 128->512 pointwise + global max pool (fused, atomicMax on relu'd values) ---------
__global__ __launch_bounds__(512) void pool_kernel(const float* __restrict__ f, const float* __restrict__ Wp,
    const float* __restrict__ bp, float* __restrict__ pooled) {
  __shared__ float xsh[128];
  const int o = threadIdx.x;
  const int b = blockIdx.x >> 3, chunk = blockIdx.x & 7;
  float wc[128];
#pragma unroll
  for (int c = 0; c < 128; ++c) wc[c] = Wp[(size_t)c*512 + o];
  const float bo = bp[o];
  float m = -finf();
  for (int n = chunk * 128; n < chunk * 128 + 128; ++n) {
    if (o < 128) xsh[o] = f[((size_t)b*BN + n)*128 + o];
    __syncthreads();
    float z = bo;
    const float4* p = (const float4*)xsh;
#pragma unroll
    for (int c = 0; c < 32; ++c) {
      const float4 v = p[c];
      z += v.x*wc[4*c+0] + v.y*wc[4*c+1] + v.z*wc[4*c+2] + v.w*wc[4*c+3];
    }
    m = fmaxf(m, z);
    __syncthreads();
  }
  m = fmaxf(m, 0.0f);   // relu(max z) == max relu(z); non-negative -> int-bit atomicMax is order-correct
  atomicMax((int*)(pooled + (size_t)b*512 + o), __float_as_int(m));
}

// ---------------- classifier head 512->256(relu)->40 ----------------
__global__ __launch_bounds__(256) void head_kernel(const float* __restrict__ pooled,
    const float* __restrict__ Wt1, const float* __restrict__ bt1,
    const float* __restrict__ Wt2, const float* __restrict__ bt2,
    float* __restrict__ out) {
  __shared__ float psh[512];
  __shared__ float h1sh[256];
  const int t = threadIdx.x, b = blockIdx.x;
  psh[t]       = pooled[(size_t)b*512 + t];
  psh[t + 256] = pooled[(size_t)b*512 + t + 256];
  __syncthreads();
  float z = bt1[t];
  for (int j = 0; j < 512; ++j) z += psh[j] * Wt1[(size_t)j*256 + t];
  h1sh[t] = fmaxf(z, 0.0f);
  __syncthreads();
  if (t < 40) {
    float z2 = bt2[t];
    for (int j = 0; j < 256; ++j) z2 += h1sh[j] * Wt2[(size_t)j*40 + t];
    out[(size_t)b*40 + t] = z2;
  }
}

extern "C" void kernel_launch(void* const* d_in, const int* in_sizes, int n_in,
                              void* d_out, int out_size, void* d_ws, size_t ws_size,
                              hipStream_t stream) {
  const float* x   = (const float*)d_in[0];
  // d_in[1] = batch indices (unused: equal-sized clouds)
  const float* W1  = (const float*)d_in[2];
  const float* B1  = (const float*)d_in[3];
  const float* W2  = (const float*)d_in[4];
  const float* B2  = (const float*)d_in[5];
  const float* W3  = (const float*)d_in[6];
  const float* B3  = (const float*)d_in[7];
  const float* W4  = (const float*)d_in[8];
  const float* B4  = (const float*)d_in[9];
  const float* Wp  = (const float*)d_in[10];
  const float* bp  = (const float*)d_in[11];
  const float* Wt1 = (const float*)d_in[12];
  const float* bt1 = (const float*)d_in[13];
  const float* Wt2 = (const float*)d_in[14];
  const float* bt2 = (const float*)d_in[15];
  float* out = (float*)d_out;

  // workspace layout (bytes, 256-aligned)
  char* ws = (char*)d_ws;
  const size_t OFF_SQ     = 0;           //  32768*4      = 131072
  const size_t OFF_IDX1   = 131072;      //  32768*20*4   = 2621440
  const size_t OFF_OUT1   = 2752512;     //  32768*64*4   = 8388608
  const size_t OFF_IDX2   = 11141120;    //  32768*20*4   = 2621440
  const size_t OFF_OUT2   = 13762560;    //  32768*128*4  = 16777216
  const size_t OFF_POOLED = 30539776;    //  32*512*4     = 65536
  const size_t WS_NEEDED  = 30605312;
  if (ws_size < WS_NEEDED) return;       // fail loudly (validation will catch it)

  float* sqbuf  = (float*)(ws + OFF_SQ);
  int*   idx1   = (int*)  (ws + OFF_IDX1);
  float* out1   = (float*)(ws + OFF_OUT1);
  int*   idx2   = (int*)  (ws + OFF_IDX2);
  float* out2   = (float*)(ws + OFF_OUT2);
  float* pooled = (float*)(ws + OFF_POOLED);
  // hi/lo bf16 split arrays alias the out2 region (4 MB each; out2 is 16.7 MB and is
  // only written by edge2_mfma AFTER knn64_mfma has consumed hi/lo — same stream).
  unsigned short* hib = (unsigned short*)(ws + OFF_OUT2);
  unsigned short* lob = (unsigned short*)(ws + OFF_OUT2 + 4194304);

  knn3_kernel      <<<NROWS/4,     256, 0, stream>>>(x, idx1);
  edge1_mfma_kernel<<<NROWS/4,     256, 0, stream>>>(x, idx1, W1, B1, W2, B2, W3, B3,
                                                     out1, hib, lob, sqbuf);
  knn64_mfma_kernel<<<NROWS/16,    1024, 0, stream>>>(hib, lob, sqbuf, idx2);
  edge2_mfma_kernel<<<NROWS/4,     256, 0, stream>>>(out1, idx2, W4, B4, out2);
  hipMemsetAsync(pooled, 0, NB*512*sizeof(float), stream);
  pool_kernel      <<<NB*8,        512, 0, stream>>>(out2, Wp, bp, pooled);
  head_kernel      <<<NB,          256, 0, stream>>>(pooled, Wt1, bt1, Wt2, bt2, out);
}